// Round 1
// baseline (297.498 us; speedup 1.0000x reference)
//
#include <hip/hip_runtime.h>
#include <hip/hip_bf16.h>

// ---------------------------------------------------------------------------
// Problem constants: B=16, N=512, DIN=128, DH=256
//   out = [node_logits 8192x8192 | graph_logits 16x16 | div_loss]
// All heavy matmuls run as bf16 MFMA (16x16x32) NT GEMMs: C = A @ Bt^T,
// A:[M,K] bf16 row-major, Bt:[Nn,K] bf16 row-major. fp32 accumulate.
// ---------------------------------------------------------------------------

using bf16x8 = __attribute__((ext_vector_type(8))) short;
using f32x4  = __attribute__((ext_vector_type(4))) float;

__device__ __forceinline__ unsigned short f2b(float f) {
    union { float f; unsigned int u; } x; x.f = f;
    unsigned int r = x.u + 0x7FFFu + ((x.u >> 16) & 1u);   // RNE
    return (unsigned short)(r >> 16);
}

// ---------------- elementwise fp32 -> bf16 (x4 vectorized) ----------------
__global__ __launch_bounds__(256) void conv_f2b(const float* __restrict__ in,
                                                unsigned short* __restrict__ out,
                                                long n4) {
    long i = (long)blockIdx.x * 256 + threadIdx.x;
    if (i >= n4) return;
    float4 v = reinterpret_cast<const float4*>(in)[i];
    ushort4 o; o.x = f2b(v.x); o.y = f2b(v.y); o.z = f2b(v.z); o.w = f2b(v.w);
    reinterpret_cast<ushort4*>(out)[i] = o;
}

// ---------------- tiled transpose fp32 in -> bf16 out (weights) ----------------
__global__ void transpose_f2b(const float* __restrict__ in,
                              unsigned short* __restrict__ out, int R, int C) {
    __shared__ float t[32][33];
    int c0 = blockIdx.x * 32, r0 = blockIdx.y * 32;
    int x = threadIdx.x, y = threadIdx.y;   // block (32,8)
    for (int i = 0; i < 32; i += 8) t[y + i][x] = in[(long)(r0 + y + i) * C + c0 + x];
    __syncthreads();
    for (int i = 0; i < 32; i += 8)
        out[(long)(c0 + y + i) * R + r0 + x] = f2b(t[x][y + i]);
}

// ---------------- tiled batched transpose bf16 -> bf16 ----------------
__global__ void transpose_b2b(const unsigned short* __restrict__ in,
                              unsigned short* __restrict__ out,
                              int R, int C, long sIn, long sOut) {
    __shared__ unsigned short t[32][34];
    const unsigned short* ip = in + (long)blockIdx.z * sIn;
    unsigned short* op = out + (long)blockIdx.z * sOut;
    int c0 = blockIdx.x * 32, r0 = blockIdx.y * 32;
    int x = threadIdx.x, y = threadIdx.y;   // block (32,8)
    for (int i = 0; i < 32; i += 8) t[y + i][x] = ip[(long)(r0 + y + i) * C + c0 + x];
    __syncthreads();
    for (int i = 0; i < 32; i += 8)
        op[(long)(c0 + y + i) * R + r0 + x] = t[x][y + i];
}

// ---------------- MFMA NT GEMM, 128x128 tile, BK=64, 4 waves ----------------
// EPI bit0 = PReLU(alpha from device scalar), bit1 = +bias[col]
#define BM 128
#define BN 128
#define BK 64
#define LDK 72   // +8 bf16 pad: fragment reads 2-way bank alias only (free)

template<int EPI, bool WF, bool WB>
__global__ __launch_bounds__(256) void gemm_nt(
    const unsigned short* __restrict__ A, const unsigned short* __restrict__ Bt,
    float* __restrict__ Cf, unsigned short* __restrict__ Cb,
    int M, int Nn, int K, long sA, long sB, long sC,
    const float* __restrict__ bias, const float* __restrict__ alpha_ptr)
{
    __shared__ unsigned short As[BM][LDK];
    __shared__ unsigned short Bs[BN][LDK];
    const int b = blockIdx.z;
    A  += (long)b * sA;
    Bt += (long)b * sB;
    const long cbase = (long)b * sC;
    const int tile_m = blockIdx.y * BM;
    const int tile_n = blockIdx.x * BN;
    const int tid  = threadIdx.x;
    const int lane = tid & 63;
    const int wave = tid >> 6;
    const int wm = (wave >> 1) << 6;   // 2x2 wave grid, 64x64 each
    const int wn = (wave & 1) << 6;

    f32x4 acc[4][4] = {};

    const int lr = tid >> 3;           // 0..31 (row group for staging)
    const int lc = (tid & 7) << 3;     // k-chunk 0,8,...,56

    for (int k0 = 0; k0 < K; k0 += BK) {
        #pragma unroll
        for (int i = 0; i < 4; ++i) {
            int r = lr + i * 32;
            uint4 va = *reinterpret_cast<const uint4*>(A + (long)(tile_m + r) * K + k0 + lc);
            *reinterpret_cast<uint4*>(&As[r][lc]) = va;
            uint4 vb = *reinterpret_cast<const uint4*>(Bt + (long)(tile_n + r) * K + k0 + lc);
            *reinterpret_cast<uint4*>(&Bs[r][lc]) = vb;
        }
        __syncthreads();
        #pragma unroll
        for (int ks = 0; ks < 2; ++ks) {
            const int kk = ks * 32 + ((lane >> 4) << 3);   // A/B frag: k = 8*(lane/16)+j
            bf16x8 af[4], bq[4];
            #pragma unroll
            for (int mi = 0; mi < 4; ++mi)
                af[mi] = *reinterpret_cast<const bf16x8*>(&As[wm + (lane & 15) + mi * 16][kk]);
            #pragma unroll
            for (int ni = 0; ni < 4; ++ni)
                bq[ni] = *reinterpret_cast<const bf16x8*>(&Bs[wn + (lane & 15) + ni * 16][kk]);
            #pragma unroll
            for (int mi = 0; mi < 4; ++mi)
                #pragma unroll
                for (int ni = 0; ni < 4; ++ni)
                    acc[mi][ni] = __builtin_amdgcn_mfma_f32_16x16x32_bf16(
                        af[mi], bq[ni], acc[mi][ni], 0, 0, 0);
        }
        __syncthreads();
    }

    const float alpha = (EPI & 1) ? alpha_ptr[0] : 0.f;
    const int c0 = lane & 15;            // C/D: col = lane&15, row = 4*(lane>>4)+j
    const int r0 = (lane >> 4) << 2;
    #pragma unroll
    for (int ni = 0; ni < 4; ++ni) {
        const int col = tile_n + wn + ni * 16 + c0;
        const float bv = (EPI & 2) ? bias[col] : 0.f;
        #pragma unroll
        for (int mi = 0; mi < 4; ++mi) {
            #pragma unroll
            for (int j = 0; j < 4; ++j) {
                const int row = tile_m + wm + mi * 16 + r0 + j;
                float v = acc[mi][ni][j] + bv;
                if (EPI & 1) v = (v >= 0.f) ? v : alpha * v;
                const long idx = cbase + (long)row * Nn + col;
                if (WF) Cf[idx] = v;
                if (WB) Cb[idx] = f2b(v);
            }
        }
    }
}

// ---------------- row L2 normalize (rows of length 256) ----------------
template<bool WFOUT, bool WBOUT>
__global__ __launch_bounds__(256) void l2norm_rows(const float* __restrict__ in,
                                                   float* __restrict__ outf,
                                                   unsigned short* __restrict__ outb) {
    long row = blockIdx.x;
    float v = in[row * 256 + threadIdx.x];
    float s = v * v;
    #pragma unroll
    for (int o = 32; o; o >>= 1) s += __shfl_xor(s, o);
    __shared__ float red[4];
    if ((threadIdx.x & 63) == 0) red[threadIdx.x >> 6] = s;
    __syncthreads();
    s = red[0] + red[1] + red[2] + red[3];
    float d = fmaxf(sqrtf(s), 1e-12f);
    float r = v / d;
    if (WFOUT) outf[row * 256 + threadIdx.x] = r;
    if (WBOUT) outb[row * 256 + threadIdx.x] = f2b(r);
}

// ---------------- masked softmax * drop_mask -> bf16 att ----------------
__global__ __launch_bounds__(256) void att_softmax(const float* __restrict__ scores,
                                                   const float* __restrict__ adj,
                                                   const float* __restrict__ drop,
                                                   unsigned short* __restrict__ att) {
    long base = ((long)blockIdx.y * 512 + blockIdx.x) * 512;
    int t = threadIdx.x;
    float a0 = adj[base + t], a1 = adj[base + t + 256];
    float s0 = scores[base + t], s1 = scores[base + t + 256];
    bool m0 = a0 > 0.f, m1 = a1 > 0.f;
    float mx = fmaxf(m0 ? s0 : -1e30f, m1 ? s1 : -1e30f);
    #pragma unroll
    for (int o = 32; o; o >>= 1) mx = fmaxf(mx, __shfl_xor(mx, o));
    __shared__ float redm[4], reds[4];
    if ((t & 63) == 0) redm[t >> 6] = mx;
    __syncthreads();
    mx = fmaxf(fmaxf(redm[0], redm[1]), fmaxf(redm[2], redm[3]));
    float e0 = m0 ? __expf(s0 - mx) : 0.f;
    float e1 = m1 ? __expf(s1 - mx) : 0.f;
    float sm = e0 + e1;
    #pragma unroll
    for (int o = 32; o; o >>= 1) sm += __shfl_xor(sm, o);
    if ((t & 63) == 0) reds[t >> 6] = sm;
    __syncthreads();
    sm = reds[0] + reds[1] + reds[2] + reds[3];
    float inv = 1.f / sm;
    att[base + t]       = f2b(e0 * inv * drop[base + t]);
    att[base + t + 256] = f2b(e1 * inv * drop[base + t + 256]);
}

// ---------------- mean over N (per batch, 256 cols) ----------------
__global__ __launch_bounds__(256) void mean_rows(const float* __restrict__ h,
                                                 float* __restrict__ c) {
    int b = blockIdx.x, t = threadIdx.x;
    const float* p = h + (long)b * 512 * 256 + t;
    float s = 0.f;
    for (int n = 0; n < 512; ++n) s += p[(long)n * 256];
    c[b * 256 + t] = s * (1.f / 512.f);
}

// ---------------- diversity loss: mean over rows of sum (q-k)^2 ----------------
__global__ __launch_bounds__(256) void divloss_part(const float* __restrict__ q,
                                                    const float* __restrict__ k,
                                                    float* __restrict__ part) {
    long t = (long)blockIdx.x * 256 + threadIdx.x;   // 65536 threads
    float s = 0.f;
    for (long i = t; i < 2097152; i += 65536) { float d = q[i] - k[i]; s += d * d; }
    #pragma unroll
    for (int o = 32; o; o >>= 1) s += __shfl_xor(s, o);
    __shared__ float red[4];
    if ((threadIdx.x & 63) == 0) red[threadIdx.x >> 6] = s;
    __syncthreads();
    if (threadIdx.x == 0) part[blockIdx.x] = red[0] + red[1] + red[2] + red[3];
}

__global__ __launch_bounds__(256) void divloss_final(const float* __restrict__ part,
                                                     float* __restrict__ out) {
    float s = part[threadIdx.x];
    #pragma unroll
    for (int o = 32; o; o >>= 1) s += __shfl_xor(s, o);
    __shared__ float red[4];
    if ((threadIdx.x & 63) == 0) red[threadIdx.x >> 6] = s;
    __syncthreads();
    if (threadIdx.x == 0) out[0] = (red[0] + red[1] + red[2] + red[3]) * (1.f / 8192.f);
}

// ---------------- graph logits 16x16 ----------------
__global__ __launch_bounds__(256) void graph16(const float* __restrict__ c1n,
                                               const float* __restrict__ c2n,
                                               float* __restrict__ out) {
    int i = threadIdx.x >> 4, j = threadIdx.x & 15;
    float s = 0.f;
    for (int h = 0; h < 256; ++h) s += c1n[i * 256 + h] * c2n[j * 256 + h];
    out[i * 16 + j] = s;
}

// ---------------------------------------------------------------------------
// Workspace layout (bytes). Total needed: 70,254,592 (~67 MB).
// Regions are reused only after the last reader of the previous tenant
// (single stream => sequential).
// ---------------------------------------------------------------------------
static constexpr long OFF_SEQ_BF = 0;                         // [8192,128] bf16
static constexpr long OFF_FC1T   = 2097152;                   // [256,128] bf16
static constexpr long OFF_FC2T   = OFF_FC1T + 65536;
static constexpr long OFF_QWT    = OFF_FC2T + 65536;          // [256,256] bf16
static constexpr long OFF_KWT    = OFF_QWT + 131072;
static constexpr long OFF_VW1T   = OFF_KWT + 131072;
static constexpr long OFF_VW2T   = OFF_VW1T + 131072;
static constexpr long OFF_C1     = OFF_VW2T + 131072;         // [16,256] f32
static constexpr long OFF_C2     = OFF_C1 + 16384;
static constexpr long OFF_PART   = OFF_C2 + 16384;            // 256 f32
static constexpr long OFF_ADJATT = 3145728;    // 8 MB: adj_bf, then att_bf
static constexpr long OFF_DIFFBF = OFF_ADJATT + 8388608;      // 8 MB
static constexpr long OFF_FTSOUT = OFF_DIFFBF + 8388608;      // 4 MB: fts_bf -> out_bf
static constexpr long OFF_TBUF   = OFF_FTSOUT + 4194304;      // 4 MB: ftsT/outT/fts2T
static constexpr long OFF_QF     = OFF_TBUF + 4194304;        // 8 MB f32: q_f -> h1_f
static constexpr long OFF_KF     = OFF_QF + 8388608;          // 8 MB f32: k_f -> h2_f
static constexpr long OFF_QBF    = OFF_KF + 8388608;          // 4 MB: q_bf -> agg -> fts2_bf
static constexpr long OFF_KBF    = OFF_QBF + 4194304;         // 4 MB: k_bf -> t1_bf
static constexpr long OFF_SCORES = OFF_KBF + 4194304;         // 16 MB f32: scores; then n1,n2

extern "C" void kernel_launch(void* const* d_in, const int* in_sizes, int n_in,
                              void* d_out, int out_size, void* d_ws, size_t ws_size,
                              hipStream_t stream) {
    const float* seq      = (const float*)d_in[0];
    const float* adj      = (const float*)d_in[1];
    const float* diff     = (const float*)d_in[2];
    const float* drop     = (const float*)d_in[3];
    const float* fc1_w    = (const float*)d_in[4];
    const float* q_w      = (const float*)d_in[5];
    const float* k_w      = (const float*)d_in[6];
    const float* v_w1     = (const float*)d_in[7];
    const float* v_w2     = (const float*)d_in[8];
    const float* fc2_w    = (const float*)d_in[9];
    const float* bias1    = (const float*)d_in[10];
    const float* bias2    = (const float*)d_in[11];
    const float* prelu1_a = (const float*)d_in[12];
    const float* prelu2_a = (const float*)d_in[13];
    const float* v_prelu  = (const float*)d_in[14];
    float* out = (float*)d_out;

    char* ws = (char*)d_ws;
    unsigned short* seq_bf  = (unsigned short*)(ws + OFF_SEQ_BF);
    unsigned short* fc1T    = (unsigned short*)(ws + OFF_FC1T);
    unsigned short* fc2T    = (unsigned short*)(ws + OFF_FC2T);
    unsigned short* qwT     = (unsigned short*)(ws + OFF_QWT);
    unsigned short* kwT     = (unsigned short*)(ws + OFF_KWT);
    unsigned short* vw1T    = (unsigned short*)(ws + OFF_VW1T);
    unsigned short* vw2T    = (unsigned short*)(ws + OFF_VW2T);
    float*          c1      = (float*)(ws + OFF_C1);
    float*          c2      = (float*)(ws + OFF_C2);
    float*          part    = (float*)(ws + OFF_PART);
    unsigned short* adj_bf  = (unsigned short*)(ws + OFF_ADJATT);
    unsigned short* att_bf  = (unsigned short*)(ws + OFF_ADJATT);   // after G2
    unsigned short* diff_bf = (unsigned short*)(ws + OFF_DIFFBF);
    unsigned short* fts_bf  = (unsigned short*)(ws + OFF_FTSOUT);
    unsigned short* out_bf  = (unsigned short*)(ws + OFF_FTSOUT);   // after T1
    unsigned short* tbuf    = (unsigned short*)(ws + OFF_TBUF);
    float*          q_f     = (float*)(ws + OFF_QF);
    float*          h1_f    = (float*)(ws + OFF_QF);                // after divloss
    float*          k_f     = (float*)(ws + OFF_KF);
    float*          h2_f    = (float*)(ws + OFF_KF);                // after divloss
    unsigned short* q_bf    = (unsigned short*)(ws + OFF_QBF);
    unsigned short* agg_bf  = (unsigned short*)(ws + OFF_QBF);      // after G4
    unsigned short* fts2_bf = (unsigned short*)(ws + OFF_QBF);      // after G6
    unsigned short* k_bf    = (unsigned short*)(ws + OFF_KBF);
    unsigned short* t1_bf   = (unsigned short*)(ws + OFF_KBF);      // after G4
    float*          scores  = (float*)(ws + OFF_SCORES);
    unsigned short* n1_bf   = (unsigned short*)(ws + OFF_SCORES);           // after softmax
    unsigned short* n2_bf   = (unsigned short*)(ws + OFF_SCORES + 4194304); // after softmax

    const dim3 tb(32, 8);

    // --- conversions ---
    conv_f2b<<<1024, 256, 0, stream>>>(seq, seq_bf, 262144);
    conv_f2b<<<4096, 256, 0, stream>>>(adj, adj_bf, 1048576);
    conv_f2b<<<4096, 256, 0, stream>>>(diff, diff_bf, 1048576);
    transpose_f2b<<<dim3(8, 4), tb, 0, stream>>>(fc1_w, fc1T, 128, 256);
    transpose_f2b<<<dim3(8, 4), tb, 0, stream>>>(fc2_w, fc2T, 128, 256);
    transpose_f2b<<<dim3(8, 8), tb, 0, stream>>>(q_w, qwT, 256, 256);
    transpose_f2b<<<dim3(8, 8), tb, 0, stream>>>(k_w, kwT, 256, 256);
    transpose_f2b<<<dim3(8, 8), tb, 0, stream>>>(v_w1, vw1T, 256, 256);
    transpose_f2b<<<dim3(8, 8), tb, 0, stream>>>(v_w2, vw2T, 256, 256);

    // --- G1: fts = seq @ fc1_w  [8192,256] ---
    gemm_nt<0, false, true><<<dim3(2, 64, 1), 256, 0, stream>>>(
        seq_bf, fc1T, nullptr, fts_bf, 8192, 256, 128, 0, 0, 0, nullptr, nullptr);
    // T1: ftsT per batch [256,512]
    transpose_b2b<<<dim3(8, 16, 16), tb, 0, stream>>>(fts_bf, tbuf, 512, 256, 131072, 131072);
    // --- G2: out = adj @ fts (batched) ---
    gemm_nt<0, false, true><<<dim3(2, 4, 16), 256, 0, stream>>>(
        adj_bf, tbuf, nullptr, out_bf, 512, 256, 512, 262144, 131072, 131072, nullptr, nullptr);
    // T2: outT per batch
    transpose_b2b<<<dim3(8, 16, 16), tb, 0, stream>>>(out_bf, tbuf, 512, 256, 131072, 131072);

    // --- G3: q_pre / k_pre ---
    gemm_nt<0, true, false><<<dim3(2, 64, 1), 256, 0, stream>>>(
        out_bf, qwT, q_f, nullptr, 8192, 256, 256, 0, 0, 0, nullptr, nullptr);
    gemm_nt<0, true, false><<<dim3(2, 64, 1), 256, 0, stream>>>(
        out_bf, kwT, k_f, nullptr, 8192, 256, 256, 0, 0, 0, nullptr, nullptr);
    // normalize (in-place f32 + bf16 copy)
    l2norm_rows<true, true><<<8192, 256, 0, stream>>>(q_f, q_f, q_bf);
    l2norm_rows<true, true><<<8192, 256, 0, stream>>>(k_f, k_f, k_bf);
    // div_loss
    divloss_part<<<256, 256, 0, stream>>>(q_f, k_f, part);
    divloss_final<<<1, 256, 0, stream>>>(part, out + 67109120);

    // --- G4: scores = q @ k^T (batched) ---
    gemm_nt<0, true, false><<<dim3(4, 4, 16), 256, 0, stream>>>(
        q_bf, k_bf, scores, nullptr, 512, 512, 256, 131072, 131072, 262144, nullptr, nullptr);
    // masked softmax * drop -> bf16 att (overwrites adj_bf region)
    att_softmax<<<dim3(512, 16), 256, 0, stream>>>(scores, adj, drop, att_bf);

    // --- G5: agg = att @ out (batched; Bt = outT) ---
    gemm_nt<0, false, true><<<dim3(2, 4, 16), 256, 0, stream>>>(
        att_bf, tbuf, nullptr, agg_bf, 512, 256, 512, 262144, 131072, 131072, nullptr, nullptr);
    // --- G6: t1 = prelu(agg @ v_w1, v_prelu_a) ---
    gemm_nt<1, false, true><<<dim3(2, 64, 1), 256, 0, stream>>>(
        agg_bf, vw1T, nullptr, t1_bf, 8192, 256, 256, 0, 0, 0, nullptr, v_prelu);
    // --- G7: h1 = prelu(t1 @ v_w2 + bias1, prelu1_a) ---
    gemm_nt<3, true, false><<<dim3(2, 64, 1), 256, 0, stream>>>(
        t1_bf, vw2T, h1_f, nullptr, 8192, 256, 256, 0, 0, 0, bias1, prelu1_a);

    // --- G8/G9: h2 branch ---
    gemm_nt<0, false, true><<<dim3(2, 64, 1), 256, 0, stream>>>(
        seq_bf, fc2T, nullptr, fts2_bf, 8192, 256, 128, 0, 0, 0, nullptr, nullptr);
    transpose_b2b<<<dim3(8, 16, 16), tb, 0, stream>>>(fts2_bf, tbuf, 512, 256, 131072, 131072);
    gemm_nt<3, true, false><<<dim3(2, 4, 16), 256, 0, stream>>>(
        diff_bf, tbuf, h2_f, nullptr, 512, 256, 512, 262144, 131072, 131072, bias2, prelu2_a);

    // --- readout ---
    mean_rows<<<16, 256, 0, stream>>>(h1_f, c1);
    mean_rows<<<16, 256, 0, stream>>>(h2_f, c2);
    l2norm_rows<true, false><<<16, 256, 0, stream>>>(c1, c1, nullptr);
    l2norm_rows<true, false><<<16, 256, 0, stream>>>(c2, c2, nullptr);
    graph16<<<1, 256, 0, stream>>>(c1, c2, out + 67108864);

    // --- node logits ---
    l2norm_rows<false, true><<<8192, 256, 0, stream>>>(h1_f, nullptr, n1_bf);
    l2norm_rows<false, true><<<8192, 256, 0, stream>>>(h2_f, nullptr, n2_bf);
    gemm_nt<0, true, false><<<dim3(64, 64, 1), 256, 0, stream>>>(
        n1_bf, n2_bf, out, nullptr, 8192, 8192, 256, 0, 0, 0, nullptr, nullptr);

    (void)in_sizes; (void)n_in; (void)out_size; (void)ws_size;
}

// Round 2
// 268.981 us; speedup vs baseline: 1.1060x; 1.1060x over previous
//
#include <hip/hip_runtime.h>
#include <hip/hip_bf16.h>

// ---------------------------------------------------------------------------
// B=16, N=512, DIN=128, DH=256
// out = [node_logits 8192x8192 f32 | graph_logits 16x16 | div_loss]
// All matmuls: bf16 MFMA 16x16x32 NT GEMM (C = A @ Bt^T), m97-structure:
// global_load_lds(16B) -> linear [128][64] LDS, 128x128 tile, 4 waves, BK=64.
// ---------------------------------------------------------------------------

using bf16x8 = __attribute__((ext_vector_type(8))) short;
using f32x4  = __attribute__((ext_vector_type(4))) float;

__device__ __forceinline__ unsigned short f2b(float f) {
    union { float f; unsigned int u; } x; x.f = f;
    unsigned int r = x.u + 0x7FFFu + ((x.u >> 16) & 1u);   // RNE
    return (unsigned short)(r >> 16);
}

__device__ __forceinline__ void gload_lds16(const void* g, void* l) {
    __builtin_amdgcn_global_load_lds(
        (const __attribute__((address_space(1))) void*)g,
        (__attribute__((address_space(3))) void*)l, 16, 0, 0);
}

// ---------------- fused fp32->bf16 conversion: seq | adj | diff ----------------
__global__ __launch_bounds__(256) void conv3(const float* __restrict__ seq,
                                             const float* __restrict__ adj,
                                             const float* __restrict__ diff,
                                             unsigned short* __restrict__ seq_bf,
                                             unsigned short* __restrict__ adj_bf,
                                             unsigned short* __restrict__ diff_bf) {
    long i = (long)blockIdx.x * 256 + threadIdx.x;   // quad index
    const float* src; unsigned short* dst; long off;
    if (i < 262144)       { src = seq;  dst = seq_bf;  off = i; }
    else if (i < 1310720) { src = adj;  dst = adj_bf;  off = i - 262144; }
    else                  { src = diff; dst = diff_bf; off = i - 1310720; }
    float4 v = reinterpret_cast<const float4*>(src)[off];
    ushort4 o; o.x = f2b(v.x); o.y = f2b(v.y); o.z = f2b(v.z); o.w = f2b(v.w);
    reinterpret_cast<ushort4*>(dst)[off] = o;
}

// ---------------- all 6 weight transposes (fp32 in -> bf16 out) ----------------
__global__ void wtrans6(const float* __restrict__ fc1, const float* __restrict__ fc2,
                        const float* __restrict__ qw,  const float* __restrict__ kw,
                        const float* __restrict__ v1,  const float* __restrict__ v2,
                        unsigned short* fc1T, unsigned short* fc2T,
                        unsigned short* qwT,  unsigned short* kwT,
                        unsigned short* v1T,  unsigned short* v2T) {
    __shared__ float t[32][33];
    const int z = blockIdx.z;
    const float* in; unsigned short* op; int R;
    const int C = 256;
    if      (z == 0) { in = fc1; op = fc1T; R = 128; }
    else if (z == 1) { in = fc2; op = fc2T; R = 128; }
    else if (z == 2) { in = qw;  op = qwT;  R = 256; }
    else if (z == 3) { in = kw;  op = kwT;  R = 256; }
    else if (z == 4) { in = v1;  op = v1T;  R = 256; }
    else             { in = v2;  op = v2T;  R = 256; }
    int c0 = blockIdx.x * 32, r0 = blockIdx.y * 32;
    if (r0 >= R) return;
    int x = threadIdx.x, y = threadIdx.y;   // block (32,8)
    for (int i = 0; i < 32; i += 8) t[y + i][x] = in[(long)(r0 + y + i) * C + c0 + x];
    __syncthreads();
    for (int i = 0; i < 32; i += 8)
        op[(long)(c0 + y + i) * R + r0 + x] = f2b(t[x][y + i]);
}

// ---------------- MFMA NT GEMM (m97 structure) ----------------
// EPI bit0 = PReLU(alpha), bit1 = +bias[col]. WF: f32 C. WB: bf16 C. WT: bf16 C^T.
#define BM 128
#define BN 128
#define BK 64

template<int EPI, bool WF, bool WB, bool WT, bool SWZ>
__global__ __launch_bounds__(256) void gemm_nt(
    const unsigned short* __restrict__ A, const unsigned short* __restrict__ Bt,
    float* __restrict__ Cf, unsigned short* __restrict__ Cb, unsigned short* __restrict__ Ct,
    int M, int Nn, int K, int lda, int ldb, int ldc, int ldt,
    long sA, long sB, long sC, long sT,
    const float* __restrict__ bias, const float* __restrict__ alpha_ptr)
{
    __shared__ unsigned short As[BM][BK];   // linear: global_load_lds dest
    __shared__ unsigned short Bs[BN][BK];
    const int b = blockIdx.z;
    A  += (long)b * sA;
    Bt += (long)b * sB;
    const long cbase = (long)b * sC;
    const long tbase = (long)b * sT;

    int tx, ty;
    if (SWZ) {   // bijective XCD swizzle (grid % 8 == 0)
        int bid = blockIdx.y * gridDim.x + blockIdx.x;
        int nwg = gridDim.x * gridDim.y;
        int cpx = nwg >> 3;
        int s = (bid & 7) * cpx + (bid >> 3);
        tx = s % gridDim.x; ty = s / gridDim.x;
    } else { tx = blockIdx.x; ty = blockIdx.y; }
    const int tile_m = ty * BM;
    const int tile_n = tx * BN;

    const int tid  = threadIdx.x;
    const int lane = tid & 63;
    const int wave = tid >> 6;
    const int wm = (wave >> 1) << 6;   // 2x2 wave grid, 64x64 each
    const int wn = (wave & 1) << 6;
    const int lrow = lane >> 3;        // 0..7 within staged 8-row chunk
    const int lcol = (lane & 7) << 3;  // element col 0,8,..,56

    f32x4 acc[4][4] = {};

    for (int k0 = 0; k0 < K; k0 += BK) {
        #pragma unroll
        for (int i = 0; i < 4; ++i) {
            const int rb = (i * 4 + wave) * 8;    // 8-row chunk base
            gload_lds16(A  + (long)(tile_m + rb + lrow) * lda + k0 + lcol, &As[rb][0]);
            gload_lds16(Bt + (long)(tile_n + rb + lrow) * ldb + k0 + lcol, &Bs[rb][0]);
        }
        __syncthreads();
        #pragma unroll
        for (int ks = 0; ks < 2; ++ks) {
            const int kk = ks * 32 + ((lane >> 4) << 3);
            bf16x8 af[4], bq[4];
            #pragma unroll
            for (int mi = 0; mi < 4; ++mi)
                af[mi] = *reinterpret_cast<const bf16x8*>(&As[wm + (lane & 15) + mi * 16][kk]);
            #pragma unroll
            for (int ni = 0; ni < 4; ++ni)
                bq[ni] = *reinterpret_cast<const bf16x8*>(&Bs[wn + (lane & 15) + ni * 16][kk]);
            #pragma unroll
            for (int mi = 0; mi < 4; ++mi)
                #pragma unroll
                for (int ni = 0; ni < 4; ++ni)
                    acc[mi][ni] = __builtin_amdgcn_mfma_f32_16x16x32_bf16(
                        af[mi], bq[ni], acc[mi][ni], 0, 0, 0);
        }
        __syncthreads();
    }

    const float alpha = (EPI & 1) ? alpha_ptr[0] : 0.f;
    const int c0 = lane & 15;            // C/D: col = lane&15, row = 4*(lane>>4)+j
    const int r0 = (lane >> 4) << 2;
    #pragma unroll
    for (int ni = 0; ni < 4; ++ni) {
        const int col = tile_n + wn + ni * 16 + c0;
        const float bv = (EPI & 2) ? bias[col] : 0.f;
        #pragma unroll
        for (int mi = 0; mi < 4; ++mi) {
            const int row0 = tile_m + wm + mi * 16 + r0;
            float v[4];
            #pragma unroll
            for (int j = 0; j < 4; ++j) {
                float x = acc[mi][ni][j] + bv;
                if (EPI & 1) x = (x >= 0.f) ? x : alpha * x;
                v[j] = x;
            }
            if (WF) {
                #pragma unroll
                for (int j = 0; j < 4; ++j)
                    Cf[cbase + (long)(row0 + j) * ldc + col] = v[j];
            }
            if (WB) {
                #pragma unroll
                for (int j = 0; j < 4; ++j)
                    Cb[cbase + (long)(row0 + j) * ldc + col] = f2b(v[j]);
            }
            if (WT) {   // C^T: 4 rows contiguous -> ushort4
                ushort4 o; o.x = f2b(v[0]); o.y = f2b(v[1]); o.z = f2b(v[2]); o.w = f2b(v[3]);
                *reinterpret_cast<ushort4*>(&Ct[tbase + (long)col * ldt + row0]) = o;
            }
        }
    }
}

// ---------------- l2norm(q)+l2norm(k)+divloss row partial ----------------
__global__ __launch_bounds__(256) void qk_post(const float* __restrict__ qk,
                                               unsigned short* __restrict__ q_bf,
                                               unsigned short* __restrict__ k_bf,
                                               float* __restrict__ rowpart) {
    long row = blockIdx.x; int t = threadIdx.x;
    float v = qk[row * 512 + t];
    float w = qk[row * 512 + 256 + t];
    float sq = v * v, sk = w * w;
    #pragma unroll
    for (int o = 32; o; o >>= 1) { sq += __shfl_xor(sq, o); sk += __shfl_xor(sk, o); }
    __shared__ float rq[4], rk[4], rd[4];
    if ((t & 63) == 0) { rq[t >> 6] = sq; rk[t >> 6] = sk; }
    __syncthreads();
    sq = rq[0] + rq[1] + rq[2] + rq[3];
    sk = rk[0] + rk[1] + rk[2] + rk[3];
    float qn = v / fmaxf(sqrtf(sq), 1e-12f);
    float kn = w / fmaxf(sqrtf(sk), 1e-12f);
    q_bf[row * 256 + t] = f2b(qn);
    k_bf[row * 256 + t] = f2b(kn);
    float d = qn - kn, sd = d * d;
    #pragma unroll
    for (int o = 32; o; o >>= 1) sd += __shfl_xor(sd, o);
    if ((t & 63) == 0) rd[t >> 6] = sd;
    __syncthreads();
    if (t == 0) rowpart[row] = rd[0] + rd[1] + rd[2] + rd[3];
}

__global__ __launch_bounds__(256) void divloss_final(const float* __restrict__ rowpart,
                                                     float* __restrict__ out) {
    int t = threadIdx.x;
    float s = 0.f;
    for (int i = t; i < 8192; i += 256) s += rowpart[i];
    #pragma unroll
    for (int o = 32; o; o >>= 1) s += __shfl_xor(s, o);
    __shared__ float red[4];
    if ((t & 63) == 0) red[t >> 6] = s;
    __syncthreads();
    if (t == 0) out[0] = (red[0] + red[1] + red[2] + red[3]) * (1.f / 8192.f);
}

// ---------------- masked softmax * drop_mask -> bf16 att ----------------
__global__ __launch_bounds__(256) void att_softmax(const float* __restrict__ scores,
                                                   const unsigned short* __restrict__ adj_bf,
                                                   const float* __restrict__ drop,
                                                   unsigned short* __restrict__ att) {
    long base = ((long)blockIdx.y * 512 + blockIdx.x) * 512;
    int t = threadIdx.x;
    unsigned short a0 = adj_bf[base + t], a1 = adj_bf[base + t + 256];
    float s0 = scores[base + t], s1 = scores[base + t + 256];
    bool m0 = a0 != 0, m1 = a1 != 0;    // adj >= 0, so nonzero bf16 <=> > 0
    float mx = fmaxf(m0 ? s0 : -1e30f, m1 ? s1 : -1e30f);
    #pragma unroll
    for (int o = 32; o; o >>= 1) mx = fmaxf(mx, __shfl_xor(mx, o));
    __shared__ float redm[4], reds[4];
    if ((t & 63) == 0) redm[t >> 6] = mx;
    __syncthreads();
    mx = fmaxf(fmaxf(redm[0], redm[1]), fmaxf(redm[2], redm[3]));
    float e0 = m0 ? __expf(s0 - mx) : 0.f;
    float e1 = m1 ? __expf(s1 - mx) : 0.f;
    float sm = e0 + e1;
    #pragma unroll
    for (int o = 32; o; o >>= 1) sm += __shfl_xor(sm, o);
    if ((t & 63) == 0) reds[t >> 6] = sm;
    __syncthreads();
    sm = reds[0] + reds[1] + reds[2] + reds[3];
    float inv = 1.f / sm;
    att[base + t]       = f2b(e0 * inv * drop[base + t]);
    att[base + t + 256] = f2b(e1 * inv * drop[base + t + 256]);
}

// ---------------- means of h1,h2 over N ----------------
__global__ __launch_bounds__(256) void mean32(const float* __restrict__ h1,
                                              const float* __restrict__ h2,
                                              float* __restrict__ c1,
                                              float* __restrict__ c2) {
    int b = blockIdx.x, t = threadIdx.x;
    const float* p = (b < 16 ? h1 + (long)b * 131072 : h2 + (long)(b - 16) * 131072) + t;
    float s = 0.f;
    for (int n = 0; n < 512; ++n) s += p[(long)n * 256];
    float* dst = (b < 16) ? (c1 + b * 256) : (c2 + (b - 16) * 256);
    dst[t] = s * (1.f / 512.f);
}

// ---------------- normalize c1,c2 + 16x16 graph logits ----------------
__global__ __launch_bounds__(256) void graphf(const float* __restrict__ c1,
                                              const float* __restrict__ c2,
                                              float* __restrict__ out) {
    __shared__ float a[16][256], bsm[16][256];
    int t = threadIdx.x, g = t >> 4, l = t & 15;
    float va[16], vb[16]; float s1 = 0.f, s2 = 0.f;
    #pragma unroll
    for (int i = 0; i < 16; ++i) {
        va[i] = c1[g * 256 + l + i * 16]; s1 += va[i] * va[i];
        vb[i] = c2[g * 256 + l + i * 16]; s2 += vb[i] * vb[i];
    }
    #pragma unroll
    for (int o = 8; o; o >>= 1) { s1 += __shfl_xor(s1, o, 16); s2 += __shfl_xor(s2, o, 16); }
    float d1 = fmaxf(sqrtf(s1), 1e-12f), d2 = fmaxf(sqrtf(s2), 1e-12f);
    #pragma unroll
    for (int i = 0; i < 16; ++i) {
        a[g][l + i * 16] = va[i] / d1;
        bsm[g][l + i * 16] = vb[i] / d2;
    }
    __syncthreads();
    int ii = t >> 4, jj = t & 15;
    float s = 0.f;
    for (int h = 0; h < 256; ++h) s += a[ii][h] * bsm[jj][h];
    out[ii * 16 + jj] = s;
}

// ---------------- fused row-l2norm of h1,h2 -> n1_bf,n2_bf ----------------
__global__ __launch_bounds__(256) void nnorm(const float* __restrict__ h1,
                                             const float* __restrict__ h2,
                                             unsigned short* __restrict__ n1,
                                             unsigned short* __restrict__ n2) {
    long row = blockIdx.x; int t = threadIdx.x;
    const float* src; unsigned short* dst;
    if (row < 8192) { src = h1 + row * 256;            dst = n1 + row * 256; }
    else            { src = h2 + (row - 8192) * 256;   dst = n2 + (row - 8192) * 256; }
    float v = src[t];
    float s = v * v;
    #pragma unroll
    for (int o = 32; o; o >>= 1) s += __shfl_xor(s, o);
    __shared__ float red[4];
    if ((t & 63) == 0) red[t >> 6] = s;
    __syncthreads();
    s = red[0] + red[1] + red[2] + red[3];
    dst[t] = f2b(v / fmaxf(sqrtf(s), 1e-12f));
}

// ---------------------------------------------------------------------------
// Workspace layout (bytes). End = 70,254,592 (same footprint as round 1).
// ---------------------------------------------------------------------------
static constexpr long OFF_SEQ_BF  = 0;                          // [8192,128] bf16, 2MB
static constexpr long OFF_FC1T    = 2097152;                    // [256,128] bf16
static constexpr long OFF_FC2T    = OFF_FC1T + 65536;
static constexpr long OFF_QWT     = OFF_FC2T + 65536;           // [256,256] bf16 (kwT follows!)
static constexpr long OFF_KWT     = OFF_QWT + 131072;
static constexpr long OFF_VW1T    = OFF_KWT + 131072;
static constexpr long OFF_VW2T    = OFF_VW1T + 131072;
static constexpr long OFF_C1      = OFF_VW2T + 131072;          // [16,256] f32
static constexpr long OFF_C2      = OFF_C1 + 16384;
static constexpr long OFF_ROWPART = OFF_C2 + 16384;             // 8192 f32, 32KB
static constexpr long OFF_ADJATT  = 3145728;                    // 8MB: adj_bf -> att_bf
static constexpr long OFF_DIFFBF  = OFF_ADJATT + 8388608;       // 8MB
static constexpr long OFF_FTST    = OFF_DIFFBF + 8388608;       // 4MB: ftsT [256,8192]
static constexpr long OFF_OUTT    = OFF_FTST + 4194304;         // 4MB: outT [16][256,512]
static constexpr long OFF_QF      = OFF_OUTT + 4194304;         // 16MB: qk_f; later h1_f (8MB)
static constexpr long OFF_KF      = OFF_QF + 8388608;           //   second half: h2_f
static constexpr long OFF_QBF     = OFF_KF + 8388608;           // 4MB: q_bf -> agg_bf -> fts2T
static constexpr long OFF_KBF     = OFF_QBF + 4194304;          // 4MB: k_bf -> t1_bf
static constexpr long OFF_SCORES  = OFF_KBF + 4194304;          // 16.8MB: out_bf -> scores -> n1,n2

extern "C" void kernel_launch(void* const* d_in, const int* in_sizes, int n_in,
                              void* d_out, int out_size, void* d_ws, size_t ws_size,
                              hipStream_t stream) {
    const float* seq      = (const float*)d_in[0];
    const float* adj      = (const float*)d_in[1];
    const float* diff     = (const float*)d_in[2];
    const float* drop     = (const float*)d_in[3];
    const float* fc1_w    = (const float*)d_in[4];
    const float* q_w      = (const float*)d_in[5];
    const float* k_w      = (const float*)d_in[6];
    const float* v_w1     = (const float*)d_in[7];
    const float* v_w2     = (const float*)d_in[8];
    const float* fc2_w    = (const float*)d_in[9];
    const float* bias1    = (const float*)d_in[10];
    const float* bias2    = (const float*)d_in[11];
    const float* prelu1_a = (const float*)d_in[12];
    const float* prelu2_a = (const float*)d_in[13];
    const float* v_prelu  = (const float*)d_in[14];
    float* out = (float*)d_out;

    char* ws = (char*)d_ws;
    unsigned short* seq_bf  = (unsigned short*)(ws + OFF_SEQ_BF);
    unsigned short* fc1T    = (unsigned short*)(ws + OFF_FC1T);
    unsigned short* fc2T    = (unsigned short*)(ws + OFF_FC2T);
    unsigned short* qwT     = (unsigned short*)(ws + OFF_QWT);   // kwT contiguous after
    unsigned short* kwT     = (unsigned short*)(ws + OFF_KWT);
    unsigned short* vw1T    = (unsigned short*)(ws + OFF_VW1T);
    unsigned short* vw2T    = (unsigned short*)(ws + OFF_VW2T);
    float*          c1      = (float*)(ws + OFF_C1);
    float*          c2      = (float*)(ws + OFF_C2);
    float*          rowpart = (float*)(ws + OFF_ROWPART);
    unsigned short* adj_bf  = (unsigned short*)(ws + OFF_ADJATT);
    unsigned short* att_bf  = (unsigned short*)(ws + OFF_ADJATT);   // after G2
    unsigned short* diff_bf = (unsigned short*)(ws + OFF_DIFFBF);
    unsigned short* ftsT    = (unsigned short*)(ws + OFF_FTST);     // [256][8192]
    unsigned short* outT    = (unsigned short*)(ws + OFF_OUTT);     // [16][256][512]
    float*          qk_f    = (float*)(ws + OFF_QF);                // [8192][512]
    float*          h1_f    = (float*)(ws + OFF_QF);                // after qk_post
    float*          h2_f    = (float*)(ws + OFF_KF);
    unsigned short* q_bf    = (unsigned short*)(ws + OFF_QBF);
    unsigned short* agg_bf  = (unsigned short*)(ws + OFF_QBF);      // after G4
    unsigned short* fts2T   = (unsigned short*)(ws + OFF_QBF);      // after G6  [256][8192]
    unsigned short* k_bf    = (unsigned short*)(ws + OFF_KBF);
    unsigned short* t1_bf   = (unsigned short*)(ws + OFF_KBF);      // after G4
    unsigned short* out_bf  = (unsigned short*)(ws + OFF_SCORES);   // [16][512][256]
    float*          scores  = (float*)(ws + OFF_SCORES);            // after G3
    unsigned short* n1_bf   = (unsigned short*)(ws + OFF_SCORES);           // after softmax
    unsigned short* n2_bf   = (unsigned short*)(ws + OFF_SCORES + 4194304);

    // --- conversions (2 launches) ---
    conv3<<<9216, 256, 0, stream>>>(seq, adj, diff, seq_bf, adj_bf, diff_bf);
    wtrans6<<<dim3(8, 8, 6), dim3(32, 8), 0, stream>>>(
        fc1_w, fc2_w, q_w, k_w, v_w1, v_w2, fc1T, fc2T, qwT, kwT, vw1T, vw2T);

    // --- G1: ftsT = fc1^T @ seq^T  [256,8192] ---
    gemm_nt<0, false, true, false, false><<<dim3(64, 2, 1), 256, 0, stream>>>(
        fc1T, seq_bf, nullptr, ftsT, nullptr,
        256, 8192, 128, 128, 128, 8192, 0, 0, 0, 0, 0, nullptr, nullptr);

    // --- G2: out = adj @ fts (batched), dual-write out_bf + outT ---
    gemm_nt<0, false, true, true, false><<<dim3(2, 4, 16), 256, 0, stream>>>(
        adj_bf, ftsT, nullptr, out_bf, outT,
        512, 256, 512, 512, 8192, 256, 512, 262144, 512, 131072, 131072, nullptr, nullptr);

    // --- G3: qk = out @ [q_w | k_w]  [8192,512] f32 ---
    gemm_nt<0, true, false, false, false><<<dim3(4, 64, 1), 256, 0, stream>>>(
        out_bf, qwT, qk_f, nullptr, nullptr,
        8192, 512, 256, 256, 256, 512, 0, 0, 0, 0, 0, nullptr, nullptr);

    // --- normalize q,k + divloss partials; final reduce ---
    qk_post<<<8192, 256, 0, stream>>>(qk_f, q_bf, k_bf, rowpart);
    divloss_final<<<1, 256, 0, stream>>>(rowpart, out + 67109120);

    // --- G4: scores = q @ k^T (batched) f32 ---
    gemm_nt<0, true, false, false, false><<<dim3(4, 4, 16), 256, 0, stream>>>(
        q_bf, k_bf, scores, nullptr, nullptr,
        512, 512, 256, 256, 256, 512, 0, 131072, 131072, 262144, 0, nullptr, nullptr);

    // --- masked softmax * drop -> att_bf (overwrites adj_bf region) ---
    att_softmax<<<dim3(512, 16), 256, 0, stream>>>(scores, adj_bf, drop, att_bf);

    // --- G5: agg = att @ out (Bt = outT) ---
    gemm_nt<0, false, true, false, false><<<dim3(2, 4, 16), 256, 0, stream>>>(
        att_bf, outT, nullptr, agg_bf, nullptr,
        512, 256, 512, 512, 512, 256, 0, 262144, 131072, 131072, 0, nullptr, nullptr);

    // --- G6: t1 = prelu(agg @ v_w1) ---
    gemm_nt<1, false, true, false, false><<<dim3(2, 64, 1), 256, 0, stream>>>(
        agg_bf, vw1T, nullptr, t1_bf, nullptr,
        8192, 256, 256, 256, 256, 256, 0, 0, 0, 0, 0, nullptr, v_prelu);

    // --- G7: h1 = prelu(t1 @ v_w2 + bias1) f32 ---
    gemm_nt<3, true, false, false, false><<<dim3(2, 64, 1), 256, 0, stream>>>(
        t1_bf, vw2T, h1_f, nullptr, nullptr,
        8192, 256, 256, 256, 256, 256, 0, 0, 0, 0, 0, bias1, prelu1_a);

    // --- G8: fts2T = fc2^T @ seq^T  [256,8192] ---
    gemm_nt<0, false, true, false, false><<<dim3(64, 2, 1), 256, 0, stream>>>(
        fc2T, seq_bf, nullptr, fts2T, nullptr,
        256, 8192, 128, 128, 128, 8192, 0, 0, 0, 0, 0, nullptr, nullptr);

    // --- G9: h2 = prelu(diff @ fts2 + bias2) f32 ---
    gemm_nt<3, true, false, false, false><<<dim3(2, 4, 16), 256, 0, stream>>>(
        diff_bf, fts2T, h2_f, nullptr, nullptr,
        512, 256, 512, 512, 8192, 256, 0, 262144, 512, 131072, 0, bias2, prelu2_a);

    // --- readout ---
    mean32<<<32, 256, 0, stream>>>(h1_f, h2_f, c1, c2);
    graphf<<<1, 256, 0, stream>>>(c1, c2, out + 67108864);
    nnorm<<<16384, 256, 0, stream>>>(h1_f, h2_f, n1_bf, n2_bf);

    // --- G10: node_logits = n1 @ n2^T  [8192,8192] f32, XCD-swizzled ---
    gemm_nt<0, true, false, false, true><<<dim3(64, 64, 1), 256, 0, stream>>>(
        n1_bf, n2_bf, out, nullptr, nullptr,
        8192, 8192, 256, 256, 256, 8192, 0, 0, 0, 0, 0, nullptr, nullptr);

    (void)in_sizes; (void)n_in; (void)out_size; (void)ws_size;
}

// Round 3
// 239.770 us; speedup vs baseline: 1.2408x; 1.1218x over previous
//
#include <hip/hip_runtime.h>
#include <hip/hip_bf16.h>

// ---------------------------------------------------------------------------
// B=16, N=512, DIN=128, DH=256
// out = [node_logits 8192x8192 f32 | graph_logits 16x16 | div_loss]
// bf16 MFMA 16x16x32 NT GEMMs (C = A @ Bt^T), m97 staging:
// global_load_lds(16B) -> linear [TBM][64] LDS, TBM in {64,128}, 4 waves.
// ---------------------------------------------------------------------------

using bf16x8 = __attribute__((ext_vector_type(8))) short;
using f32x4  = __attribute__((ext_vector_type(4))) float;

__device__ __forceinline__ unsigned short f2b(float f) {
    union { float f; unsigned int u; } x; x.f = f;
    unsigned int r = x.u + 0x7FFFu + ((x.u >> 16) & 1u);   // RNE
    return (unsigned short)(r >> 16);
}
__device__ __forceinline__ float b2f(unsigned short u) {
    union { unsigned int u; float f; } x; x.u = (unsigned int)u << 16;
    return x.f;
}
__device__ __forceinline__ void gload_lds16(const void* g, void* l) {
    __builtin_amdgcn_global_load_lds(
        (const __attribute__((address_space(1))) void*)g,
        (__attribute__((address_space(3))) void*)l, 16, 0, 0);
}

// ---------------- fused fp32->bf16 conversion: seq | adj | diff ----------------
__global__ __launch_bounds__(256) void conv3(const float* __restrict__ seq,
                                             const float* __restrict__ adj,
                                             const float* __restrict__ diff,
                                             unsigned short* __restrict__ seq_bf,
                                             unsigned short* __restrict__ adj_bf,
                                             unsigned short* __restrict__ diff_bf) {
    long i = (long)blockIdx.x * 256 + threadIdx.x;   // quad index
    const float* src; unsigned short* dst; long off;
    if (i < 262144)       { src = seq;  dst = seq_bf;  off = i; }
    else if (i < 1310720) { src = adj;  dst = adj_bf;  off = i - 262144; }
    else                  { src = diff; dst = diff_bf; off = i - 1310720; }
    float4 v = reinterpret_cast<const float4*>(src)[off];
    ushort4 o; o.x = f2b(v.x); o.y = f2b(v.y); o.z = f2b(v.z); o.w = f2b(v.w);
    reinterpret_cast<ushort4*>(dst)[off] = o;
}

// ---------------- all 6 weight transposes (fp32 in -> bf16 out) ----------------
__global__ void wtrans6(const float* __restrict__ fc1, const float* __restrict__ fc2,
                        const float* __restrict__ qw,  const float* __restrict__ kw,
                        const float* __restrict__ v1,  const float* __restrict__ v2,
                        unsigned short* fc1T, unsigned short* fc2T,
                        unsigned short* qwT,  unsigned short* kwT,
                        unsigned short* v1T,  unsigned short* v2T) {
    __shared__ float t[32][33];
    const int z = blockIdx.z;
    const float* in; unsigned short* op; int R;
    const int C = 256;
    if      (z == 0) { in = fc1; op = fc1T; R = 128; }
    else if (z == 1) { in = fc2; op = fc2T; R = 128; }
    else if (z == 2) { in = qw;  op = qwT;  R = 256; }
    else if (z == 3) { in = kw;  op = kwT;  R = 256; }
    else if (z == 4) { in = v1;  op = v1T;  R = 256; }
    else             { in = v2;  op = v2T;  R = 256; }
    int c0 = blockIdx.x * 32, r0 = blockIdx.y * 32;
    if (r0 >= R) return;
    int x = threadIdx.x, y = threadIdx.y;   // block (32,8)
    for (int i = 0; i < 32; i += 8) t[y + i][x] = in[(long)(r0 + y + i) * C + c0 + x];
    __syncthreads();
    for (int i = 0; i < 32; i += 8)
        op[(long)(c0 + y + i) * R + r0 + x] = f2b(t[x][y + i]);
}

// ---------------- MFMA NT GEMM (m97 staging), TBM x 128 tile, BK=64 ----------------
// EPI bit0 = PReLU(alpha), bit1 = +bias[col]. WF f32 / WB bf16 / WT bf16 C^T.
#define BN 128
#define BK 64

template<int TBM, int EPI, bool WF, bool WB, bool WT, bool SWZ>
__global__ __launch_bounds__(256) void gemm_nt(
    const unsigned short* __restrict__ A, const unsigned short* __restrict__ Bt,
    float* __restrict__ Cf, unsigned short* __restrict__ Cb, unsigned short* __restrict__ Ct,
    int M, int Nn, int K, int lda, int ldb, int ldc, int ldt,
    long sA, long sB, long sC, long sT,
    const float* __restrict__ bias, const float* __restrict__ alpha_ptr)
{
    constexpr int MI = TBM / 32;            // m-fragments per wave
    __shared__ unsigned short As[TBM][BK];  // linear: global_load_lds dest
    __shared__ unsigned short Bs[BN][BK];
    const int b = blockIdx.z;
    A  += (long)b * sA;
    Bt += (long)b * sB;
    const long cbase = (long)b * sC;
    const long tbase = (long)b * sT;

    int tx, ty;
    if (SWZ) {   // bijective XCD swizzle (grid % 8 == 0)
        int bid = blockIdx.y * gridDim.x + blockIdx.x;
        int nwg = gridDim.x * gridDim.y;
        int cpx = nwg >> 3;
        int s = (bid & 7) * cpx + (bid >> 3);
        tx = s % gridDim.x; ty = s / gridDim.x;
    } else { tx = blockIdx.x; ty = blockIdx.y; }
    const int tile_m = ty * TBM;
    const int tile_n = tx * BN;

    const int tid  = threadIdx.x;
    const int lane = tid & 63;
    const int wave = tid >> 6;
    const int wm = (wave >> 1) * (TBM / 2);   // 2x2 wave grid
    const int wn = (wave & 1) << 6;
    const int lrow = lane >> 3;        // 0..7 within staged 8-row chunk
    const int lcol = (lane & 7) << 3;  // element col 0,8,..,56

    f32x4 acc[MI][4] = {};

    for (int k0 = 0; k0 < K; k0 += BK) {
        #pragma unroll
        for (int i = 0; i < TBM / 32; ++i) {
            const int rb = (i * 4 + wave) * 8;
            gload_lds16(A + (long)(tile_m + rb + lrow) * lda + k0 + lcol, &As[rb][0]);
        }
        #pragma unroll
        for (int i = 0; i < 4; ++i) {
            const int rb = (i * 4 + wave) * 8;
            gload_lds16(Bt + (long)(tile_n + rb + lrow) * ldb + k0 + lcol, &Bs[rb][0]);
        }
        __syncthreads();
        #pragma unroll
        for (int ks = 0; ks < 2; ++ks) {
            const int kk = ks * 32 + ((lane >> 4) << 3);
            bf16x8 af[MI], bq[4];
            #pragma unroll
            for (int mi = 0; mi < MI; ++mi)
                af[mi] = *reinterpret_cast<const bf16x8*>(&As[wm + (lane & 15) + mi * 16][kk]);
            #pragma unroll
            for (int ni = 0; ni < 4; ++ni)
                bq[ni] = *reinterpret_cast<const bf16x8*>(&Bs[wn + (lane & 15) + ni * 16][kk]);
            #pragma unroll
            for (int mi = 0; mi < MI; ++mi)
                #pragma unroll
                for (int ni = 0; ni < 4; ++ni)
                    acc[mi][ni] = __builtin_amdgcn_mfma_f32_16x16x32_bf16(
                        af[mi], bq[ni], acc[mi][ni], 0, 0, 0);
        }
        __syncthreads();
    }

    const float alpha = (EPI & 1) ? alpha_ptr[0] : 0.f;
    const int c0 = lane & 15;            // C/D: col = lane&15, row = 4*(lane>>4)+j
    const int r0 = (lane >> 4) << 2;
    #pragma unroll
    for (int ni = 0; ni < 4; ++ni) {
        const int col = tile_n + wn + ni * 16 + c0;
        const float bv = (EPI & 2) ? bias[col] : 0.f;
        #pragma unroll
        for (int mi = 0; mi < MI; ++mi) {
            const int row0 = tile_m + wm + mi * 16 + r0;
            float v[4];
            #pragma unroll
            for (int j = 0; j < 4; ++j) {
                float x = acc[mi][ni][j] + bv;
                if (EPI & 1) x = (x >= 0.f) ? x : alpha * x;
                v[j] = x;
            }
            if (WF) {
                #pragma unroll
                for (int j = 0; j < 4; ++j)
                    Cf[cbase + (long)(row0 + j) * ldc + col] = v[j];
            }
            if (WB) {
                #pragma unroll
                for (int j = 0; j < 4; ++j)
                    Cb[cbase + (long)(row0 + j) * ldc + col] = f2b(v[j]);
            }
            if (WT) {   // C^T: 4 rows contiguous -> ushort4
                ushort4 o; o.x = f2b(v[0]); o.y = f2b(v[1]); o.z = f2b(v[2]); o.w = f2b(v[3]);
                *reinterpret_cast<ushort4*>(&Ct[tbase + (long)col * ldt + row0]) = o;
            }
        }
    }
}

// ---------------- fused GEMM + bias + PReLU + row-l2norm + col psums ----------------
// BM=32, BN=256 (full row per block, 4 waves of 32x64). Writes n_out bf16 and
// per-block column sums psum[p][256] (p = z*gridDim.y + y; 16 chunks/batch).
__global__ __launch_bounds__(256) void gemm_norm(
    const unsigned short* __restrict__ A, const unsigned short* __restrict__ Bt,
    unsigned short* __restrict__ n_out, float* __restrict__ psum,
    const float* __restrict__ bias, const float* __restrict__ alpha_ptr,
    int K, int lda, int ldb, long sA, long sB)
{
    __shared__ unsigned short As[32][BK];
    __shared__ unsigned short Bs[256][BK];
    __shared__ float rowred[32][4];
    A  += (long)blockIdx.z * sA;
    Bt += (long)blockIdx.z * sB;
    const int p = blockIdx.z * gridDim.y + blockIdx.y;
    const int arow0 = blockIdx.y * 32;
    const long grow0 = (long)p * 32;

    const int tid  = threadIdx.x;
    const int lane = tid & 63;
    const int wave = tid >> 6;
    const int wn = wave << 6;          // wave cols 64w..64w+63
    const int lrow = lane >> 3;
    const int lcol = (lane & 7) << 3;

    f32x4 acc[2][4] = {};

    for (int k0 = 0; k0 < K; k0 += BK) {
        {
            const int rb = wave * 8;   // 32 A rows: 1 issue per wave
            gload_lds16(A + (long)(arow0 + rb + lrow) * lda + k0 + lcol, &As[rb][0]);
        }
        #pragma unroll
        for (int i = 0; i < 8; ++i) {  // 256 B rows: 8 issues per wave
            const int rb = (i * 4 + wave) * 8;
            gload_lds16(Bt + (long)(rb + lrow) * ldb + k0 + lcol, &Bs[rb][0]);
        }
        __syncthreads();
        #pragma unroll
        for (int ks = 0; ks < 2; ++ks) {
            const int kk = ks * 32 + ((lane >> 4) << 3);
            bf16x8 af[2], bq[4];
            #pragma unroll
            for (int mi = 0; mi < 2; ++mi)
                af[mi] = *reinterpret_cast<const bf16x8*>(&As[(lane & 15) + mi * 16][kk]);
            #pragma unroll
            for (int ni = 0; ni < 4; ++ni)
                bq[ni] = *reinterpret_cast<const bf16x8*>(&Bs[wn + (lane & 15) + ni * 16][kk]);
            #pragma unroll
            for (int mi = 0; mi < 2; ++mi)
                #pragma unroll
                for (int ni = 0; ni < 4; ++ni)
                    acc[mi][ni] = __builtin_amdgcn_mfma_f32_16x16x32_bf16(
                        af[mi], bq[ni], acc[mi][ni], 0, 0, 0);
        }
        __syncthreads();
    }

    const float alpha = alpha_ptr[0];
    const int c0 = lane & 15;
    const int r0 = (lane >> 4) << 2;
    float rs[2][4] = {};
    #pragma unroll
    for (int ni = 0; ni < 4; ++ni) {
        const float bv = bias[wn + ni * 16 + c0];
        #pragma unroll
        for (int mi = 0; mi < 2; ++mi)
            #pragma unroll
            for (int j = 0; j < 4; ++j) {
                float x = acc[mi][ni][j] + bv;
                x = (x >= 0.f) ? x : alpha * x;
                acc[mi][ni][j] = x;
                rs[mi][j] += x * x;
            }
    }
    #pragma unroll
    for (int o = 1; o <= 8; o <<= 1)
        #pragma unroll
        for (int mi = 0; mi < 2; ++mi)
            #pragma unroll
            for (int j = 0; j < 4; ++j) rs[mi][j] += __shfl_xor(rs[mi][j], o);
    if ((lane & 15) == 0) {
        #pragma unroll
        for (int mi = 0; mi < 2; ++mi)
            #pragma unroll
            for (int j = 0; j < 4; ++j) rowred[mi * 16 + r0 + j][wave] = rs[mi][j];
    }
    __syncthreads();
    float inv[2][4];
    #pragma unroll
    for (int mi = 0; mi < 2; ++mi)
        #pragma unroll
        for (int j = 0; j < 4; ++j) {
            const int r = mi * 16 + r0 + j;
            float s = rowred[r][0] + rowred[r][1] + rowred[r][2] + rowred[r][3];
            inv[mi][j] = 1.f / fmaxf(sqrtf(s), 1e-12f);
        }
    // column partial sums over the block's 32 rows
    float cs[4];
    #pragma unroll
    for (int ni = 0; ni < 4; ++ni) {
        float s = 0.f;
        #pragma unroll
        for (int mi = 0; mi < 2; ++mi)
            #pragma unroll
            for (int j = 0; j < 4; ++j) s += acc[mi][ni][j];
        s += __shfl_xor(s, 16);
        s += __shfl_xor(s, 32);
        cs[ni] = s;
    }
    if (lane < 16) {
        #pragma unroll
        for (int ni = 0; ni < 4; ++ni)
            psum[(long)p * 256 + wn + ni * 16 + lane] = cs[ni];
    }
    // normalized bf16 rows
    #pragma unroll
    for (int ni = 0; ni < 4; ++ni)
        #pragma unroll
        for (int mi = 0; mi < 2; ++mi)
            #pragma unroll
            for (int j = 0; j < 4; ++j)
                n_out[(grow0 + mi * 16 + r0 + j) * 256 + wn + ni * 16 + c0] =
                    f2b(acc[mi][ni][j] * inv[mi][j]);
}

// ---------------- l2norm(q)+l2norm(k)+divloss row partial ----------------
__global__ __launch_bounds__(256) void qk_post(const float* __restrict__ qk,
                                               unsigned short* __restrict__ q_bf,
                                               unsigned short* __restrict__ k_bf,
                                               float* __restrict__ rowpart) {
    long row = blockIdx.x; int t = threadIdx.x;
    float v = qk[row * 512 + t];
    float w = qk[row * 512 + 256 + t];
    float sq = v * v, sk = w * w;
    #pragma unroll
    for (int o = 32; o; o >>= 1) { sq += __shfl_xor(sq, o); sk += __shfl_xor(sk, o); }
    __shared__ float rq[4], rk[4], rd[4];
    if ((t & 63) == 0) { rq[t >> 6] = sq; rk[t >> 6] = sk; }
    __syncthreads();
    sq = rq[0] + rq[1] + rq[2] + rq[3];
    sk = rk[0] + rk[1] + rk[2] + rk[3];
    float qn = v / fmaxf(sqrtf(sq), 1e-12f);
    float kn = w / fmaxf(sqrtf(sk), 1e-12f);
    q_bf[row * 256 + t] = f2b(qn);
    k_bf[row * 256 + t] = f2b(kn);
    float d = qn - kn, sd = d * d;
    #pragma unroll
    for (int o = 32; o; o >>= 1) sd += __shfl_xor(sd, o);
    if ((t & 63) == 0) rd[t >> 6] = sd;
    __syncthreads();
    if (t == 0) rowpart[row] = rd[0] + rd[1] + rd[2] + rd[3];
}

// ---------------- masked softmax * drop_mask (bf16 scores in) ----------------
__global__ __launch_bounds__(256) void att_softmax(const unsigned short* __restrict__ scores,
                                                   const unsigned short* __restrict__ adj_bf,
                                                   const float* __restrict__ drop,
                                                   unsigned short* __restrict__ att) {
    long base = ((long)blockIdx.y * 512 + blockIdx.x) * 512;
    int t = threadIdx.x;
    unsigned short a0 = adj_bf[base + t], a1 = adj_bf[base + t + 256];
    float s0 = b2f(scores[base + t]), s1 = b2f(scores[base + t + 256]);
    bool m0 = a0 != 0, m1 = a1 != 0;    // adj >= 0, so nonzero bf16 <=> > 0
    float mx = fmaxf(m0 ? s0 : -1e30f, m1 ? s1 : -1e30f);
    #pragma unroll
    for (int o = 32; o; o >>= 1) mx = fmaxf(mx, __shfl_xor(mx, o));
    __shared__ float redm[4], reds[4];
    if ((t & 63) == 0) redm[t >> 6] = mx;
    __syncthreads();
    mx = fmaxf(fmaxf(redm[0], redm[1]), fmaxf(redm[2], redm[3]));
    float e0 = m0 ? __expf(s0 - mx) : 0.f;
    float e1 = m1 ? __expf(s1 - mx) : 0.f;
    float sm = e0 + e1;
    #pragma unroll
    for (int o = 32; o; o >>= 1) sm += __shfl_xor(sm, o);
    if ((t & 63) == 0) reds[t >> 6] = sm;
    __syncthreads();
    sm = reds[0] + reds[1] + reds[2] + reds[3];
    float inv = 1.f / sm;
    att[base + t]       = f2b(e0 * inv * drop[base + t]);
    att[base + t + 256] = f2b(e1 * inv * drop[base + t + 256]);
}

// ---------------- psum reduce -> means -> norms -> graph16 + divloss ----------------
__global__ __launch_bounds__(256) void graphf2(const float* __restrict__ psum1,
                                               const float* __restrict__ psum2,
                                               const float* __restrict__ rowpart,
                                               float* __restrict__ out_g,
                                               float* __restrict__ out_div) {
    __shared__ float a[16][256], bsm[16][256];
    int t = threadIdx.x, g = t >> 4, l = t & 15;
    float va[16], vb[16]; float s1 = 0.f, s2 = 0.f;
    #pragma unroll
    for (int i = 0; i < 16; ++i) {
        const int col = l + i * 16;
        float m1 = 0.f, m2 = 0.f;
        for (int c = 0; c < 16; ++c) {
            m1 += psum1[(long)(g * 16 + c) * 256 + col];
            m2 += psum2[(long)(g * 16 + c) * 256 + col];
        }
        va[i] = m1 * (1.f / 512.f); s1 += va[i] * va[i];
        vb[i] = m2 * (1.f / 512.f); s2 += vb[i] * vb[i];
    }
    #pragma unroll
    for (int o = 8; o; o >>= 1) { s1 += __shfl_xor(s1, o, 16); s2 += __shfl_xor(s2, o, 16); }
    float d1 = fmaxf(sqrtf(s1), 1e-12f), d2 = fmaxf(sqrtf(s2), 1e-12f);
    #pragma unroll
    for (int i = 0; i < 16; ++i) {
        a[g][l + i * 16] = va[i] / d1;
        bsm[g][l + i * 16] = vb[i] / d2;
    }
    __syncthreads();
    int ii = t >> 4, jj = t & 15;
    float s = 0.f;
    for (int h = 0; h < 256; ++h) s += a[ii][h] * bsm[jj][h];
    out_g[ii * 16 + jj] = s;
    // divloss
    float ds = 0.f;
    for (int i = t; i < 8192; i += 256) ds += rowpart[i];
    #pragma unroll
    for (int o = 32; o; o >>= 1) ds += __shfl_xor(ds, o);
    __shared__ float red[4];
    if ((t & 63) == 0) red[t >> 6] = ds;
    __syncthreads();
    if (t == 0) out_div[0] = (red[0] + red[1] + red[2] + red[3]) * (1.f / 8192.f);
}

// ---------------------------------------------------------------------------
// Workspace layout (bytes). End = 70,254,592.
// ---------------------------------------------------------------------------
static constexpr long OFF_SEQ_BF  = 0;                          // [8192,128] bf16, 2MB
static constexpr long OFF_FC1T    = 2097152;                    // [256,128] bf16
static constexpr long OFF_FC2T    = OFF_FC1T + 65536;
static constexpr long OFF_QWT     = OFF_FC2T + 65536;           // [512,256] stacked q|k
static constexpr long OFF_KWT     = OFF_QWT + 131072;
static constexpr long OFF_VW1T    = OFF_KWT + 131072;
static constexpr long OFF_VW2T    = OFF_VW1T + 131072;
static constexpr long OFF_ROWPART = OFF_VW2T + 131072;          // 8192 f32, 32KB
static constexpr long OFF_ADJATT  = 3145728;                    // 8MB: adj_bf -> att_bf
static constexpr long OFF_DIFFBF  = OFF_ADJATT + 8388608;       // 8MB
static constexpr long OFF_FTST    = OFF_DIFFBF + 8388608;       // 4MB: ftsT [256,8192]
static constexpr long OFF_OUTT    = OFF_FTST + 4194304;         // 4MB: outT [16][256,512]
static constexpr long OFF_QF      = OFF_OUTT + 4194304;         // 16MB: qk_f; later psum1/2
static constexpr long OFF_QBF     = OFF_QF + 16777216;          // 4MB: q_bf -> agg_bf -> fts2T
static constexpr long OFF_KBF     = OFF_QBF + 4194304;          // 4MB: k_bf -> t1_bf
static constexpr long OFF_SCORES  = OFF_KBF + 4194304;          // 16.8MB: out_bf -> scores_bf -> n1,n2

extern "C" void kernel_launch(void* const* d_in, const int* in_sizes, int n_in,
                              void* d_out, int out_size, void* d_ws, size_t ws_size,
                              hipStream_t stream) {
    const float* seq      = (const float*)d_in[0];
    const float* adj      = (const float*)d_in[1];
    const float* diff     = (const float*)d_in[2];
    const float* drop     = (const float*)d_in[3];
    const float* fc1_w    = (const float*)d_in[4];
    const float* q_w      = (const float*)d_in[5];
    const float* k_w      = (const float*)d_in[6];
    const float* v_w1     = (const float*)d_in[7];
    const float* v_w2     = (const float*)d_in[8];
    const float* fc2_w    = (const float*)d_in[9];
    const float* bias1    = (const float*)d_in[10];
    const float* bias2    = (const float*)d_in[11];
    const float* prelu1_a = (const float*)d_in[12];
    const float* prelu2_a = (const float*)d_in[13];
    const float* v_prelu  = (const float*)d_in[14];
    float* out = (float*)d_out;

    char* ws = (char*)d_ws;
    unsigned short* seq_bf  = (unsigned short*)(ws + OFF_SEQ_BF);
    unsigned short* fc1T    = (unsigned short*)(ws + OFF_FC1T);
    unsigned short* fc2T    = (unsigned short*)(ws + OFF_FC2T);
    unsigned short* qwT     = (unsigned short*)(ws + OFF_QWT);   // kwT contiguous after
    unsigned short* kwT     = (unsigned short*)(ws + OFF_KWT);
    unsigned short* vw1T    = (unsigned short*)(ws + OFF_VW1T);
    unsigned short* vw2T    = (unsigned short*)(ws + OFF_VW2T);
    float*          rowpart = (float*)(ws + OFF_ROWPART);
    unsigned short* adj_bf  = (unsigned short*)(ws + OFF_ADJATT);
    unsigned short* att_bf  = (unsigned short*)(ws + OFF_ADJATT);   // after softmax
    unsigned short* diff_bf = (unsigned short*)(ws + OFF_DIFFBF);
    unsigned short* ftsT    = (unsigned short*)(ws + OFF_FTST);     // [256][8192]
    unsigned short* outT    = (unsigned short*)(ws + OFF_OUTT);     // [16][256][512]
    float*          qk_f    = (float*)(ws + OFF_QF);                // [8192][512]
    float*          psum1   = (float*)(ws + OFF_QF);                // after qk_post: [256][256]
    float*          psum2   = (float*)(ws + OFF_QF + 262144);       // [256][256]
    unsigned short* q_bf    = (unsigned short*)(ws + OFF_QBF);
    unsigned short* agg_bf  = (unsigned short*)(ws + OFF_QBF);      // after G5
    unsigned short* fts2T   = (unsigned short*)(ws + OFF_QBF);      // after G6  [256][8192]
    unsigned short* k_bf    = (unsigned short*)(ws + OFF_KBF);
    unsigned short* t1_bf   = (unsigned short*)(ws + OFF_KBF);      // after G6
    unsigned short* out_bf  = (unsigned short*)(ws + OFF_SCORES);   // [16][512][256]
    unsigned short* scoresb = (unsigned short*)(ws + OFF_SCORES);   // after G4 (bf16)
    unsigned short* n1_bf   = (unsigned short*)(ws + OFF_SCORES);           // after softmax
    unsigned short* n2_bf   = (unsigned short*)(ws + OFF_SCORES + 4194304);

    // --- conversions (2 launches) ---
    conv3<<<9216, 256, 0, stream>>>(seq, adj, diff, seq_bf, adj_bf, diff_bf);
    wtrans6<<<dim3(8, 8, 6), dim3(32, 8), 0, stream>>>(
        fc1_w, fc2_w, q_w, k_w, v_w1, v_w2, fc1T, fc2T, qwT, kwT, vw1T, vw2T);

    // --- G1: ftsT = fc1^T @ seq^T  [256,8192] ---
    gemm_nt<64, 0, false, true, false, false><<<dim3(64, 4, 1), 256, 0, stream>>>(
        fc1T, seq_bf, nullptr, ftsT, nullptr,
        256, 8192, 128, 128, 128, 8192, 0, 0, 0, 0, 0, nullptr, nullptr);

    // --- G2: out = adj @ fts (batched), dual-write out_bf + outT ---
    gemm_nt<64, 0, false, true, true, false><<<dim3(2, 8, 16), 256, 0, stream>>>(
        adj_bf, ftsT, nullptr, out_bf, outT,
        512, 256, 512, 512, 8192, 256, 512, 262144, 512, 131072, 131072, nullptr, nullptr);

    // --- G3: qk = out @ [q_w | k_w]  [8192,512] f32 ---
    gemm_nt<128, 0, true, false, false, false><<<dim3(4, 64, 1), 256, 0, stream>>>(
        out_bf, qwT, qk_f, nullptr, nullptr,
        8192, 512, 256, 256, 256, 512, 0, 0, 0, 0, 0, nullptr, nullptr);

    // --- normalize q,k + divloss partials ---
    qk_post<<<8192, 256, 0, stream>>>(qk_f, q_bf, k_bf, rowpart);

    // --- G4: scores = q @ k^T (batched), bf16 out ---
    gemm_nt<64, 0, false, true, false, false><<<dim3(4, 8, 16), 256, 0, stream>>>(
        q_bf, k_bf, nullptr, scoresb, nullptr,
        512, 512, 256, 256, 256, 512, 0, 131072, 131072, 262144, 0, nullptr, nullptr);

    // --- masked softmax * drop -> att_bf (in-place over adj_bf region) ---
    att_softmax<<<dim3(512, 16), 256, 0, stream>>>(scoresb, adj_bf, drop, att_bf);

    // --- G5: agg = att @ out (Bt = outT) ---
    gemm_nt<64, 0, false, true, false, false><<<dim3(2, 8, 16), 256, 0, stream>>>(
        att_bf, outT, nullptr, agg_bf, nullptr,
        512, 256, 512, 512, 512, 256, 0, 262144, 131072, 131072, 0, nullptr, nullptr);

    // --- G6: t1 = prelu(agg @ v_w1) ---
    gemm_nt<64, 1, false, true, false, false><<<dim3(2, 128, 1), 256, 0, stream>>>(
        agg_bf, vw1T, nullptr, t1_bf, nullptr,
        8192, 256, 256, 256, 256, 256, 0, 0, 0, 0, 0, nullptr, v_prelu);

    // --- G7h: h1 = prelu(t1 @ v_w2 + bias1) -> n1_bf + psum1 ---
    gemm_norm<<<dim3(1, 256, 1), 256, 0, stream>>>(
        t1_bf, vw2T, n1_bf, psum1, bias1, prelu1_a, 256, 256, 256, 0, 0);

    // --- G8: fts2T = fc2^T @ seq^T  [256,8192] (reuses QBF after agg dead) ---
    gemm_nt<64, 0, false, true, false, false><<<dim3(64, 4, 1), 256, 0, stream>>>(
        fc2T, seq_bf, nullptr, fts2T, nullptr,
        256, 8192, 128, 128, 128, 8192, 0, 0, 0, 0, 0, nullptr, nullptr);

    // --- G9h: h2 = prelu(diff @ fts2 + bias2) -> n2_bf + psum2 ---
    gemm_norm<<<dim3(1, 16, 16), 256, 0, stream>>>(
        diff_bf, fts2T, n2_bf, psum2, bias2, prelu2_a, 512, 512, 8192, 262144, 512);

    // --- readout: means, norms, graph16, divloss ---
    graphf2<<<1, 256, 0, stream>>>(psum1, psum2, rowpart, out + 67108864, out + 67109120);

    // --- G10: node_logits = n1 @ n2^T  [8192,8192] f32, XCD-swizzled ---
    gemm_nt<128, 0, true, false, false, true><<<dim3(64, 64, 1), 256, 0, stream>>>(
        n1_bf, n2_bf, out, nullptr, nullptr,
        8192, 8192, 256, 256, 256, 8192, 0, 0, 0, 0, 0, nullptr, nullptr);

    (void)in_sizes; (void)n_in; (void)out_size; (void)ws_size;
}

// Round 4
// 209.347 us; speedup vs baseline: 1.4211x; 1.1453x over previous
//
#include <hip/hip_runtime.h>
#include <hip/hip_bf16.h>

// ---------------------------------------------------------------------------
// B=16, N=512, DIN=128, DH=256
// out = [node_logits 8192x8192 f32 | graph_logits 16x16 | div_loss]
// bf16 MFMA 16x16x32 NT GEMMs; m97 staging (global_load_lds 16B -> linear LDS).
// R4: fused ATT (scores+softmax+PV), fused qk_proj (+l2norm), fused mlp_norm.
// ---------------------------------------------------------------------------

using bf16x8 = __attribute__((ext_vector_type(8))) short;
using f32x4  = __attribute__((ext_vector_type(4))) float;

__device__ __forceinline__ unsigned short f2b(float f) {
    union { float f; unsigned int u; } x; x.f = f;
    unsigned int r = x.u + 0x7FFFu + ((x.u >> 16) & 1u);   // RNE
    return (unsigned short)(r >> 16);
}
__device__ __forceinline__ void gload_lds16(const void* g, void* l) {
    __builtin_amdgcn_global_load_lds(
        (const __attribute__((address_space(1))) void*)g,
        (__attribute__((address_space(3))) void*)l, 16, 0, 0);
}

// ---------------- fused fp32->bf16 conversion: seq | adj | diff ----------------
__global__ __launch_bounds__(256) void conv3(const float* __restrict__ seq,
                                             const float* __restrict__ adj,
                                             const float* __restrict__ diff,
                                             unsigned short* __restrict__ seq_bf,
                                             unsigned short* __restrict__ adj_bf,
                                             unsigned short* __restrict__ diff_bf) {
    long i = (long)blockIdx.x * 256 + threadIdx.x;   // quad index
    const float* src; unsigned short* dst; long off;
    if (i < 262144)       { src = seq;  dst = seq_bf;  off = i; }
    else if (i < 1310720) { src = adj;  dst = adj_bf;  off = i - 262144; }
    else                  { src = diff; dst = diff_bf; off = i - 1310720; }
    float4 v = reinterpret_cast<const float4*>(src)[off];
    ushort4 o; o.x = f2b(v.x); o.y = f2b(v.y); o.z = f2b(v.z); o.w = f2b(v.w);
    reinterpret_cast<ushort4*>(dst)[off] = o;
}

// ---------------- all 6 weight transposes (fp32 in -> bf16 out) ----------------
__global__ void wtrans6(const float* __restrict__ fc1, const float* __restrict__ fc2,
                        const float* __restrict__ qw,  const float* __restrict__ kw,
                        const float* __restrict__ v1,  const float* __restrict__ v2,
                        unsigned short* fc1T, unsigned short* fc2T,
                        unsigned short* qwT,  unsigned short* kwT,
                        unsigned short* v1T,  unsigned short* v2T) {
    __shared__ float t[32][33];
    const int z = blockIdx.z;
    const float* in; unsigned short* op; int R;
    const int C = 256;
    if      (z == 0) { in = fc1; op = fc1T; R = 128; }
    else if (z == 1) { in = fc2; op = fc2T; R = 128; }
    else if (z == 2) { in = qw;  op = qwT;  R = 256; }
    else if (z == 3) { in = kw;  op = kwT;  R = 256; }
    else if (z == 4) { in = v1;  op = v1T;  R = 256; }
    else             { in = v2;  op = v2T;  R = 256; }
    int c0 = blockIdx.x * 32, r0 = blockIdx.y * 32;
    if (r0 >= R) return;
    int x = threadIdx.x, y = threadIdx.y;   // block (32,8)
    for (int i = 0; i < 32; i += 8) t[y + i][x] = in[(long)(r0 + y + i) * C + c0 + x];
    __syncthreads();
    for (int i = 0; i < 32; i += 8)
        op[(long)(c0 + y + i) * R + r0 + x] = f2b(t[x][y + i]);
}

// ---------------- MFMA NT GEMM (m97 staging), TBM x 128 tile, BK=64 ----------------
#define BN 128
#define BK 64

template<int TBM, int EPI, bool WF, bool WB, bool WT, bool SWZ>
__global__ __launch_bounds__(256) void gemm_nt(
    const unsigned short* __restrict__ A, const unsigned short* __restrict__ Bt,
    float* __restrict__ Cf, unsigned short* __restrict__ Cb, unsigned short* __restrict__ Ct,
    int M, int Nn, int K, int lda, int ldb, int ldc, int ldt,
    long sA, long sB, long sC, long sT,
    const float* __restrict__ bias, const float* __restrict__ alpha_ptr)
{
    constexpr int MI = TBM / 32;
    __shared__ unsigned short As[TBM][BK];
    __shared__ unsigned short Bs[BN][BK];
    const int b = blockIdx.z;
    A  += (long)b * sA;
    Bt += (long)b * sB;
    const long cbase = (long)b * sC;
    const long tbase = (long)b * sT;

    int tx, ty;
    if (SWZ) {
        int bid = blockIdx.y * gridDim.x + blockIdx.x;
        int nwg = gridDim.x * gridDim.y;
        int cpx = nwg >> 3;
        int s = (bid & 7) * cpx + (bid >> 3);
        tx = s % gridDim.x; ty = s / gridDim.x;
    } else { tx = blockIdx.x; ty = blockIdx.y; }
    const int tile_m = ty * TBM;
    const int tile_n = tx * BN;

    const int tid  = threadIdx.x;
    const int lane = tid & 63;
    const int wave = tid >> 6;
    const int wm = (wave >> 1) * (TBM / 2);
    const int wn = (wave & 1) << 6;
    const int lrow = lane >> 3;
    const int lcol = (lane & 7) << 3;

    f32x4 acc[MI][4] = {};

    for (int k0 = 0; k0 < K; k0 += BK) {
        #pragma unroll
        for (int i = 0; i < TBM / 32; ++i) {
            const int rb = (i * 4 + wave) * 8;
            gload_lds16(A + (long)(tile_m + rb + lrow) * lda + k0 + lcol, &As[rb][0]);
        }
        #pragma unroll
        for (int i = 0; i < 4; ++i) {
            const int rb = (i * 4 + wave) * 8;
            gload_lds16(Bt + (long)(tile_n + rb + lrow) * ldb + k0 + lcol, &Bs[rb][0]);
        }
        __syncthreads();
        #pragma unroll
        for (int ks = 0; ks < 2; ++ks) {
            const int kk = ks * 32 + ((lane >> 4) << 3);
            bf16x8 af[MI], bq[4];
            #pragma unroll
            for (int mi = 0; mi < MI; ++mi)
                af[mi] = *reinterpret_cast<const bf16x8*>(&As[wm + (lane & 15) + mi * 16][kk]);
            #pragma unroll
            for (int ni = 0; ni < 4; ++ni)
                bq[ni] = *reinterpret_cast<const bf16x8*>(&Bs[wn + (lane & 15) + ni * 16][kk]);
            #pragma unroll
            for (int mi = 0; mi < MI; ++mi)
                #pragma unroll
                for (int ni = 0; ni < 4; ++ni)
                    acc[mi][ni] = __builtin_amdgcn_mfma_f32_16x16x32_bf16(
                        af[mi], bq[ni], acc[mi][ni], 0, 0, 0);
        }
        __syncthreads();
    }

    const float alpha = (EPI & 1) ? alpha_ptr[0] : 0.f;
    const int c0 = lane & 15;
    const int r0 = (lane >> 4) << 2;
    #pragma unroll
    for (int ni = 0; ni < 4; ++ni) {
        const int col = tile_n + wn + ni * 16 + c0;
        const float bv = (EPI & 2) ? bias[col] : 0.f;
        #pragma unroll
        for (int mi = 0; mi < MI; ++mi) {
            const int row0 = tile_m + wm + mi * 16 + r0;
            float v[4];
            #pragma unroll
            for (int j = 0; j < 4; ++j) {
                float x = acc[mi][ni][j] + bv;
                if (EPI & 1) x = (x >= 0.f) ? x : alpha * x;
                v[j] = x;
            }
            if (WF) {
                #pragma unroll
                for (int j = 0; j < 4; ++j)
                    Cf[cbase + (long)(row0 + j) * ldc + col] = v[j];
            }
            if (WB) {
                #pragma unroll
                for (int j = 0; j < 4; ++j)
                    Cb[cbase + (long)(row0 + j) * ldc + col] = f2b(v[j]);
            }
            if (WT) {
                ushort4 o; o.x = f2b(v[0]); o.y = f2b(v[1]); o.z = f2b(v[2]); o.w = f2b(v[3]);
                *reinterpret_cast<ushort4*>(&Ct[tbase + (long)col * ldt + row0]) = o;
            }
        }
    }
}

// ---------------- fused GEMM + bias + PReLU + row-l2norm + col psums ----------------
// (kept from R3: used for the diff branch h2) BM=32, BN=256 full row.
__global__ __launch_bounds__(256) void gemm_norm(
    const unsigned short* __restrict__ A, const unsigned short* __restrict__ Bt,
    unsigned short* __restrict__ n_out, float* __restrict__ psum,
    const float* __restrict__ bias, const float* __restrict__ alpha_ptr,
    int K, int lda, int ldb, long sA, long sB)
{
    __shared__ unsigned short As[32][BK];
    __shared__ unsigned short Bs[256][BK];
    __shared__ float rowred[32][4];
    A  += (long)blockIdx.z * sA;
    Bt += (long)blockIdx.z * sB;
    const int p = blockIdx.z * gridDim.y + blockIdx.y;
    const int arow0 = blockIdx.y * 32;
    const long grow0 = (long)p * 32;

    const int tid  = threadIdx.x;
    const int lane = tid & 63;
    const int wave = tid >> 6;
    const int wn = wave << 6;
    const int lrow = lane >> 3;
    const int lcol = (lane & 7) << 3;

    f32x4 acc[2][4] = {};

    for (int k0 = 0; k0 < K; k0 += BK) {
        {
            const int rb = wave * 8;
            gload_lds16(A + (long)(arow0 + rb + lrow) * lda + k0 + lcol, &As[rb][0]);
        }
        #pragma unroll
        for (int i = 0; i < 8; ++i) {
            const int rb = (i * 4 + wave) * 8;
            gload_lds16(Bt + (long)(rb + lrow) * ldb + k0 + lcol, &Bs[rb][0]);
        }
        __syncthreads();
        #pragma unroll
        for (int ks = 0; ks < 2; ++ks) {
            const int kk = ks * 32 + ((lane >> 4) << 3);
            bf16x8 af[2], bq[4];
            #pragma unroll
            for (int mi = 0; mi < 2; ++mi)
                af[mi] = *reinterpret_cast<const bf16x8*>(&As[(lane & 15) + mi * 16][kk]);
            #pragma unroll
            for (int ni = 0; ni < 4; ++ni)
                bq[ni] = *reinterpret_cast<const bf16x8*>(&Bs[wn + (lane & 15) + ni * 16][kk]);
            #pragma unroll
            for (int mi = 0; mi < 2; ++mi)
                #pragma unroll
                for (int ni = 0; ni < 4; ++ni)
                    acc[mi][ni] = __builtin_amdgcn_mfma_f32_16x16x32_bf16(
                        af[mi], bq[ni], acc[mi][ni], 0, 0, 0);
        }
        __syncthreads();
    }

    const float alpha = alpha_ptr[0];
    const int c0 = lane & 15;
    const int r0 = (lane >> 4) << 2;
    float rs[2][4] = {};
    #pragma unroll
    for (int ni = 0; ni < 4; ++ni) {
        const float bv = bias[wn + ni * 16 + c0];
        #pragma unroll
        for (int mi = 0; mi < 2; ++mi)
            #pragma unroll
            for (int j = 0; j < 4; ++j) {
                float x = acc[mi][ni][j] + bv;
                x = (x >= 0.f) ? x : alpha * x;
                acc[mi][ni][j] = x;
                rs[mi][j] += x * x;
            }
    }
    #pragma unroll
    for (int o = 1; o <= 8; o <<= 1)
        #pragma unroll
        for (int mi = 0; mi < 2; ++mi)
            #pragma unroll
            for (int j = 0; j < 4; ++j) rs[mi][j] += __shfl_xor(rs[mi][j], o);
    if ((lane & 15) == 0) {
        #pragma unroll
        for (int mi = 0; mi < 2; ++mi)
            #pragma unroll
            for (int j = 0; j < 4; ++j) rowred[mi * 16 + r0 + j][wave] = rs[mi][j];
    }
    __syncthreads();
    float inv[2][4];
    #pragma unroll
    for (int mi = 0; mi < 2; ++mi)
        #pragma unroll
        for (int j = 0; j < 4; ++j) {
            const int r = mi * 16 + r0 + j;
            float s = rowred[r][0] + rowred[r][1] + rowred[r][2] + rowred[r][3];
            inv[mi][j] = 1.f / fmaxf(sqrtf(s), 1e-12f);
        }
    float cs[4];
    #pragma unroll
    for (int ni = 0; ni < 4; ++ni) {
        float s = 0.f;
        #pragma unroll
        for (int mi = 0; mi < 2; ++mi)
            #pragma unroll
            for (int j = 0; j < 4; ++j) s += acc[mi][ni][j];
        s += __shfl_xor(s, 16);
        s += __shfl_xor(s, 32);
        cs[ni] = s;
    }
    if (lane < 16) {
        #pragma unroll
        for (int ni = 0; ni < 4; ++ni)
            psum[(long)p * 256 + wn + ni * 16 + lane] = cs[ni];
    }
    #pragma unroll
    for (int ni = 0; ni < 4; ++ni)
        #pragma unroll
        for (int mi = 0; mi < 2; ++mi)
            #pragma unroll
            for (int j = 0; j < 4; ++j)
                n_out[(grow0 + mi * 16 + r0 + j) * 256 + wn + ni * 16 + c0] =
                    f2b(acc[mi][ni][j] * inv[mi][j]);
}

// ---------------- fused q/k projection + row l2norm -> q_bf,k_bf ----------------
// 32 rows/block, full 512-wide (q|k stacked weights). Waves 0,1 own q cols,
// waves 2,3 own k cols.
__global__ __launch_bounds__(256) void qk_proj(
    const unsigned short* __restrict__ outb,  // [8192][256]
    const unsigned short* __restrict__ qkT,   // [512][256]
    unsigned short* __restrict__ q_bf,        // [8192][256]
    unsigned short* __restrict__ k_bf)        // [8192][256]
{
    __shared__ unsigned short As[32 * 64];
    __shared__ unsigned short Bs[512 * 64];
    __shared__ float sred[32][4];
    const long m0 = (long)blockIdx.x * 32;
    const int tid = threadIdx.x, lane = tid & 63, wave = tid >> 6;
    const int lrow = lane >> 3, lcol = (lane & 7) << 3;
    const int hi = lane >> 4, c0 = lane & 15, r0 = hi << 2;
    const int wn = wave << 7;            // 128 cols per wave

    f32x4 acc[2][8] = {};
    for (int k0 = 0; k0 < 256; k0 += 64) {
        gload_lds16(outb + (m0 + wave * 8 + lrow) * 256 + k0 + lcol, &As[wave * 8 * 64]);
        #pragma unroll
        for (int i = 0; i < 16; ++i) {
            const int rb = (i * 4 + wave) * 8;
            gload_lds16(qkT + (long)(rb + lrow) * 256 + k0 + lcol, &Bs[rb * 64]);
        }
        __syncthreads();
        #pragma unroll
        for (int ks = 0; ks < 2; ++ks) {
            const int kk = ks * 32 + (hi << 3);
            bf16x8 af[2], bq[8];
            #pragma unroll
            for (int mi = 0; mi < 2; ++mi)
                af[mi] = *reinterpret_cast<const bf16x8*>(&As[(mi * 16 + c0) * 64 + kk]);
            #pragma unroll
            for (int ni = 0; ni < 8; ++ni)
                bq[ni] = *reinterpret_cast<const bf16x8*>(&Bs[(wn + ni * 16 + c0) * 64 + kk]);
            #pragma unroll
            for (int mi = 0; mi < 2; ++mi)
                #pragma unroll
                for (int ni = 0; ni < 8; ++ni)
                    acc[mi][ni] = __builtin_amdgcn_mfma_f32_16x16x32_bf16(
                        af[mi], bq[ni], acc[mi][ni], 0, 0, 0);
        }
        __syncthreads();
    }
    // per-row sumsq within wave (each wave's 128 cols are entirely q or k)
    float rs[2][4] = {};
    #pragma unroll
    for (int mi = 0; mi < 2; ++mi)
        #pragma unroll
        for (int ni = 0; ni < 8; ++ni)
            #pragma unroll
            for (int j = 0; j < 4; ++j) { float x = acc[mi][ni][j]; rs[mi][j] += x * x; }
    #pragma unroll
    for (int o = 1; o <= 8; o <<= 1)
        #pragma unroll
        for (int mi = 0; mi < 2; ++mi)
            #pragma unroll
            for (int j = 0; j < 4; ++j) rs[mi][j] += __shfl_xor(rs[mi][j], o);
    if (c0 == 0) {
        #pragma unroll
        for (int mi = 0; mi < 2; ++mi)
            #pragma unroll
            for (int j = 0; j < 4; ++j) sred[mi * 16 + r0 + j][wave] = rs[mi][j];
    }
    __syncthreads();
    float inv[2][4];
    #pragma unroll
    for (int mi = 0; mi < 2; ++mi)
        #pragma unroll
        for (int j = 0; j < 4; ++j) {
            const int r = mi * 16 + r0 + j;
            float sq = sred[r][0] + sred[r][1];
            float sk = sred[r][2] + sred[r][3];
            inv[mi][j] = 1.f / fmaxf(sqrtf(wave < 2 ? sq : sk), 1e-12f);
        }
    #pragma unroll
    for (int mi = 0; mi < 2; ++mi)
        #pragma unroll
        for (int ni = 0; ni < 8; ++ni)
            #pragma unroll
            for (int j = 0; j < 4; ++j) {
                const long rowg = m0 + mi * 16 + r0 + j;
                const int col = wn + ni * 16 + c0;
                unsigned short v = f2b(acc[mi][ni][j] * inv[mi][j]);
                if (wave < 2) q_bf[rowg * 256 + col] = v;
                else          k_bf[rowg * 256 + col - 256] = v;
            }
}

// ---------------- fused attention: scores -> masked softmax*drop -> P@out ----------------
// Block: 32 att rows x full 512 K-rows, batch blockIdx.y. Also emits div_loss
// row parts from the scores diagonal (||q-k||^2 = 2 - 2 q.k for unit vectors).
__global__ __launch_bounds__(256) void att_fused(
    const unsigned short* __restrict__ q_bf,   // [16][512][256]
    const unsigned short* __restrict__ k_bf,   // [16][512][256]
    const unsigned short* __restrict__ adj_bf, // [16][512][512]
    const float* __restrict__ drop,            // [16][512][512]
    const unsigned short* __restrict__ outT,   // [16][256][512]
    unsigned short* __restrict__ agg_bf,       // [16][512][256]
    float* __restrict__ rowpart)               // [8192]
{
    __shared__ unsigned char smem[69632];
    unsigned short* As  = (unsigned short*)smem;            // [32][64]   phase 1
    unsigned short* Bs  = (unsigned short*)(smem + 4096);   // [512][64]  phase 1
    unsigned short* Pls = (unsigned short*)smem;            // [32][520]  phase 2
    unsigned short* Bs2 = (unsigned short*)(smem + 34816);  // [256][64]  phase 2
    __shared__ float redm[32][4], reds[32][4];

    const int b  = blockIdx.y;
    const int m0 = blockIdx.x << 5;
    const unsigned short* qp = q_bf + (long)b * 131072 + (long)m0 * 256;
    const unsigned short* kp = k_bf + (long)b * 131072;
    const unsigned short* ot = outT + (long)b * 131072;
    const unsigned short* ap = adj_bf + ((long)b * 512 + m0) * 512;
    const float*          dp = drop   + ((long)b * 512 + m0) * 512;

    const int tid = threadIdx.x, lane = tid & 63, wave = tid >> 6;
    const int lrow = lane >> 3, lcol = (lane & 7) << 3;
    const int hi = lane >> 4, c0 = lane & 15, r0 = hi << 2;
    const int wn = wave << 7;

    // ---- phase 1: scores[32][512] = q[32,256] @ k^T ----
    f32x4 acc[2][8] = {};
    for (int k0 = 0; k0 < 256; k0 += 64) {
        gload_lds16(qp + (long)(wave * 8 + lrow) * 256 + k0 + lcol, &As[wave * 8 * 64]);
        #pragma unroll
        for (int i = 0; i < 16; ++i) {
            const int rb = (i * 4 + wave) * 8;
            gload_lds16(kp + (long)(rb + lrow) * 256 + k0 + lcol, &Bs[rb * 64]);
        }
        __syncthreads();
        #pragma unroll
        for (int ks = 0; ks < 2; ++ks) {
            const int kk = ks * 32 + (hi << 3);
            bf16x8 af[2], bq[8];
            #pragma unroll
            for (int mi = 0; mi < 2; ++mi)
                af[mi] = *reinterpret_cast<const bf16x8*>(&As[(mi * 16 + c0) * 64 + kk]);
            #pragma unroll
            for (int ni = 0; ni < 8; ++ni)
                bq[ni] = *reinterpret_cast<const bf16x8*>(&Bs[(wn + ni * 16 + c0) * 64 + kk]);
            #pragma unroll
            for (int mi = 0; mi < 2; ++mi)
                #pragma unroll
                for (int ni = 0; ni < 8; ++ni)
                    acc[mi][ni] = __builtin_amdgcn_mfma_f32_16x16x32_bf16(
                        af[mi], bq[ni], acc[mi][ni], 0, 0, 0);
        }
        __syncthreads();
    }

    // ---- mask + div_loss diag + row max ----
    float rmax[2][4];
    #pragma unroll
    for (int mi = 0; mi < 2; ++mi)
        #pragma unroll
        for (int j = 0; j < 4; ++j) rmax[mi][j] = -3.0e38f;
    #pragma unroll
    for (int mi = 0; mi < 2; ++mi)
        #pragma unroll
        for (int ni = 0; ni < 8; ++ni)
            #pragma unroll
            for (int j = 0; j < 4; ++j) {
                const int rowl = mi * 16 + r0 + j;
                const int col  = wn + ni * 16 + c0;
                float s = acc[mi][ni][j];
                if (col == m0 + rowl)
                    rowpart[(long)b * 512 + m0 + rowl] = 2.f - 2.f * s;
                bool m = ap[(long)rowl * 512 + col] != 0;
                s = m ? s : -3.0e38f;
                acc[mi][ni][j] = s;
                rmax[mi][j] = fmaxf(rmax[mi][j], s);
            }
    #pragma unroll
    for (int o = 1; o <= 8; o <<= 1)
        #pragma unroll
        for (int mi = 0; mi < 2; ++mi)
            #pragma unroll
            for (int j = 0; j < 4; ++j) rmax[mi][j] = fmaxf(rmax[mi][j], __shfl_xor(rmax[mi][j], o));
    if (c0 == 0) {
        #pragma unroll
        for (int mi = 0; mi < 2; ++mi)
            #pragma unroll
            for (int j = 0; j < 4; ++j) redm[mi * 16 + r0 + j][wave] = rmax[mi][j];
    }
    __syncthreads();
    float mx[2][4], rsum[2][4];
    #pragma unroll
    for (int mi = 0; mi < 2; ++mi)
        #pragma unroll
        for (int j = 0; j < 4; ++j) {
            const int r = mi * 16 + r0 + j;
            mx[mi][j] = fmaxf(fmaxf(redm[r][0], redm[r][1]), fmaxf(redm[r][2], redm[r][3]));
            rsum[mi][j] = 0.f;
        }
    #pragma unroll
    for (int mi = 0; mi < 2; ++mi)
        #pragma unroll
        for (int ni = 0; ni < 8; ++ni)
            #pragma unroll
            for (int j = 0; j < 4; ++j) {
                float e = __expf(acc[mi][ni][j] - mx[mi][j]);   // masked -> exp(-huge)=0
                acc[mi][ni][j] = e;
                rsum[mi][j] += e;
            }
    #pragma unroll
    for (int o = 1; o <= 8; o <<= 1)
        #pragma unroll
        for (int mi = 0; mi < 2; ++mi)
            #pragma unroll
            for (int j = 0; j < 4; ++j) rsum[mi][j] += __shfl_xor(rsum[mi][j], o);
    if (c0 == 0) {
        #pragma unroll
        for (int mi = 0; mi < 2; ++mi)
            #pragma unroll
            for (int j = 0; j < 4; ++j) reds[mi * 16 + r0 + j][wave] = rsum[mi][j];
    }
    __syncthreads();
    float inv[2][4];
    #pragma unroll
    for (int mi = 0; mi < 2; ++mi)
        #pragma unroll
        for (int j = 0; j < 4; ++j) {
            const int r = mi * 16 + r0 + j;
            inv[mi][j] = 1.f / (reds[r][0] + reds[r][1] + reds[r][2] + reds[r][3]);
        }
    // P = e * inv * drop -> LDS bf16 (stride 520: +8 pad -> 2-way bank alias only)
    #pragma unroll
    for (int mi = 0; mi < 2; ++mi)
        #pragma unroll
        for (int ni = 0; ni < 8; ++ni)
            #pragma unroll
            for (int j = 0; j < 4; ++j) {
                const int rowl = mi * 16 + r0 + j;
                const int col  = wn + ni * 16 + c0;
                float p = acc[mi][ni][j] * inv[mi][j] * dp[(long)rowl * 512 + col];
                Pls[rowl * 520 + col] = f2b(p);
            }
    __syncthreads();

    // ---- phase 2: agg[32][256] = P[32,512] @ out[512,256] (Bt = outT) ----
    f32x4 acc2[2][4] = {};
    for (int k0 = 0; k0 < 512; k0 += 64) {
        #pragma unroll
        for (int i = 0; i < 8; ++i) {
            const int rb = (i * 4 + wave) * 8;
            gload_lds16(ot + (long)(rb + lrow) * 512 + k0 + lcol, &Bs2[rb * 64]);
        }
        __syncthreads();
        #pragma unroll
        for (int ks = 0; ks < 2; ++ks) {
            const int kk = ks * 32 + (hi << 3);
            bf16x8 af[2], bq[4];
            #pragma unroll
            for (int mi = 0; mi < 2; ++mi)
                af[mi] = *reinterpret_cast<const bf16x8*>(&Pls[(mi * 16 + c0) * 520 + k0 + kk]);
            #pragma unroll
            for (int ni = 0; ni < 4; ++ni)
                bq[ni] = *reinterpret_cast<const bf16x8*>(&Bs2[((wave << 6) + ni * 16 + c0) * 64 + kk]);
            #pragma unroll
            for (int mi = 0; mi < 2; ++mi)
                #pragma unroll
                for (int ni = 0; ni < 4; ++ni)
                    acc2[mi][ni] = __builtin_amdgcn_mfma_f32_16x16x32_bf16(
                        af[mi], bq[ni], acc2[mi][ni], 0, 0, 0);
        }
        __syncthreads();
    }
    #pragma unroll
    for (int mi = 0; mi < 2; ++mi)
        #pragma unroll
        for (int ni = 0; ni < 4; ++ni)
            #pragma unroll
            for (int j = 0; j < 4; ++j) {
                const int rowl = mi * 16 + r0 + j;
                const int col  = (wave << 6) + ni * 16 + c0;
                agg_bf[((long)b * 512 + m0 + rowl) * 256 + col] = f2b(acc2[mi][ni][j]);
            }
}

// ---------------- fused MLP: t1=prelu(agg@w1); h1=prelu(t1@w2+b); norm+psum ----------------
__global__ __launch_bounds__(256) void mlp_norm(
    const unsigned short* __restrict__ agg,   // [8192][256]
    const unsigned short* __restrict__ w1T,   // [256][256]
    const unsigned short* __restrict__ w2T,   // [256][256]
    const float* __restrict__ bias,           // [256]
    const float* __restrict__ av, const float* __restrict__ a1,
    unsigned short* __restrict__ n_out,       // [8192][256]
    float* __restrict__ psum)                 // [256][256]
{
    __shared__ unsigned char smem[49664];
    unsigned short* As  = (unsigned short*)smem;            // [32][64]   phase 1
    unsigned short* Bs  = (unsigned short*)(smem + 4096);   // [256][64]  phase 1
    unsigned short* T   = (unsigned short*)smem;            // [32][264]  phase 2
    unsigned short* Bs2 = (unsigned short*)(smem + 16896);  // [256][64]  phase 2
    __shared__ float rowred[32][4];

    const int p = blockIdx.x;
    const long row0 = (long)p * 32;
    const int tid = threadIdx.x, lane = tid & 63, wave = tid >> 6;
    const int lrow = lane >> 3, lcol = (lane & 7) << 3;
    const int hi = lane >> 4, c0 = lane & 15, r0 = hi << 2;
    const int wn = wave << 6;

    f32x4 acc[2][4] = {};
    for (int k0 = 0; k0 < 256; k0 += 64) {
        gload_lds16(agg + (row0 + wave * 8 + lrow) * 256 + k0 + lcol, &As[wave * 8 * 64]);
        #pragma unroll
        for (int i = 0; i < 8; ++i) {
            const int rb = (i * 4 + wave) * 8;
            gload_lds16(w1T + (long)(rb + lrow) * 256 + k0 + lcol, &Bs[rb * 64]);
        }
        __syncthreads();
        #pragma unroll
        for (int ks = 0; ks < 2; ++ks) {
            const int kk = ks * 32 + (hi << 3);
            bf16x8 af[2], bq[4];
            #pragma unroll
            for (int mi = 0; mi < 2; ++mi)
                af[mi] = *reinterpret_cast<const bf16x8*>(&As[(mi * 16 + c0) * 64 + kk]);
            #pragma unroll
            for (int ni = 0; ni < 4; ++ni)
                bq[ni] = *reinterpret_cast<const bf16x8*>(&Bs[(wn + ni * 16 + c0) * 64 + kk]);
            #pragma unroll
            for (int mi = 0; mi < 2; ++mi)
                #pragma unroll
                for (int ni = 0; ni < 4; ++ni)
                    acc[mi][ni] = __builtin_amdgcn_mfma_f32_16x16x32_bf16(
                        af[mi], bq[ni], acc[mi][ni], 0, 0, 0);
        }
        __syncthreads();
    }
    const float alphav = av[0];
    #pragma unroll
    for (int mi = 0; mi < 2; ++mi)
        #pragma unroll
        for (int ni = 0; ni < 4; ++ni)
            #pragma unroll
            for (int j = 0; j < 4; ++j) {
                const int rowl = mi * 16 + r0 + j;
                const int col  = wn + ni * 16 + c0;
                float x = acc[mi][ni][j];
                x = (x >= 0.f) ? x : alphav * x;
                T[rowl * 264 + col] = f2b(x);
            }
    __syncthreads();

    f32x4 acc2[2][4] = {};
    for (int k0 = 0; k0 < 256; k0 += 64) {
        #pragma unroll
        for (int i = 0; i < 8; ++i) {
            const int rb = (i * 4 + wave) * 8;
            gload_lds16(w2T + (long)(rb + lrow) * 256 + k0 + lcol, &Bs2[rb * 64]);
        }
        __syncthreads();
        #pragma unroll
        for (int ks = 0; ks < 2; ++ks) {
            const int kk = ks * 32 + (hi << 3);
            bf16x8 af[2], bq[4];
            #pragma unroll
            for (int mi = 0; mi < 2; ++mi)
                af[mi] = *reinterpret_cast<const bf16x8*>(&T[(mi * 16 + c0) * 264 + k0 + kk]);
            #pragma unroll
            for (int ni = 0; ni < 4; ++ni)
                bq[ni] = *reinterpret_cast<const bf16x8*>(&Bs2[(wn + ni * 16 + c0) * 64 + kk]);
            #pragma unroll
            for (int mi = 0; mi < 2; ++mi)
                #pragma unroll
                for (int ni = 0; ni < 4; ++ni)
                    acc2[mi][ni] = __builtin_amdgcn_mfma_f32_16x16x32_bf16(
                        af[mi], bq[ni], acc2[mi][ni], 0, 0, 0);
        }
        __syncthreads();
    }
    const float alpha1 = a1[0];
    float rs[2][4] = {};
    #pragma unroll
    for (int ni = 0; ni < 4; ++ni) {
        const float bv = bias[wn + ni * 16 + c0];
        #pragma unroll
        for (int mi = 0; mi < 2; ++mi)
            #pragma unroll
            for (int j = 0; j < 4; ++j) {
                float x = acc2[mi][ni][j] + bv;
                x = (x >= 0.f) ? x : alpha1 * x;
                acc2[mi][ni][j] = x;
                rs[mi][j] += x * x;
            }
    }
    #pragma unroll
    for (int o = 1; o <= 8; o <<= 1)
        #pragma unroll
        for (int mi = 0; mi < 2; ++mi)
            #pragma unroll
            for (int j = 0; j < 4; ++j) rs[mi][j] += __shfl_xor(rs[mi][j], o);
    if (c0 == 0) {
        #pragma unroll
        for (int mi = 0; mi < 2; ++mi)
            #pragma unroll
            for (int j = 0; j < 4; ++j) rowred[mi * 16 + r0 + j][wave] = rs[mi][j];
    }
    __syncthreads();
    float inv[2][4];
    #pragma unroll
    for (int mi = 0; mi < 2; ++mi)
        #pragma unroll
        for (int j = 0; j < 4; ++j) {
            const int r = mi * 16 + r0 + j;
            float s = rowred[r][0] + rowred[r][1] + rowred[r][2] + rowred[r][3];
            inv[mi][j] = 1.f / fmaxf(sqrtf(s), 1e-12f);
        }
    float cs[4];
    #pragma unroll
    for (int ni = 0; ni < 4; ++ni) {
        float s = 0.f;
        #pragma unroll
        for (int mi = 0; mi < 2; ++mi)
            #pragma unroll
            for (int j = 0; j < 4; ++j) s += acc2[mi][ni][j];
        s += __shfl_xor(s, 16);
        s += __shfl_xor(s, 32);
        cs[ni] = s;
    }
    if (lane < 16) {
        #pragma unroll
        for (int ni = 0; ni < 4; ++ni)
            psum[(long)p * 256 + wn + ni * 16 + lane] = cs[ni];
    }
    #pragma unroll
    for (int mi = 0; mi < 2; ++mi)
        #pragma unroll
        for (int ni = 0; ni < 4; ++ni)
            #pragma unroll
            for (int j = 0; j < 4; ++j)
                n_out[(row0 + mi * 16 + r0 + j) * 256 + wn + ni * 16 + c0] =
                    f2b(acc2[mi][ni][j] * inv[mi][j]);
}

// ---------------- psum -> normalized graph means (parallel) ----------------
__global__ __launch_bounds__(256) void creduce(const float* __restrict__ psum1,
                                               const float* __restrict__ psum2,
                                               float* __restrict__ c1n,
                                               float* __restrict__ c2n) {
    const int which = blockIdx.x & 1, g = blockIdx.x >> 1;
    const float* ps = which ? psum2 : psum1;
    float* cn = which ? c2n : c1n;
    const int t = threadIdx.x;
    float s = 0.f;
    #pragma unroll
    for (int c = 0; c < 16; ++c) s += ps[(long)(g * 16 + c) * 256 + t];
    s *= (1.f / 512.f);
    float ss = s * s;
    #pragma unroll
    for (int o = 32; o; o >>= 1) ss += __shfl_xor(ss, o);
    __shared__ float red[4];
    if ((t & 63) == 0) red[t >> 6] = ss;
    __syncthreads();
    float tot = red[0] + red[1] + red[2] + red[3];
    cn[g * 256 + t] = s / fmaxf(sqrtf(tot), 1e-12f);
}

// ---------------- graph logits 16x16 + div_loss ----------------
__global__ __launch_bounds__(256) void graphf3(const float* __restrict__ c1n,
                                               const float* __restrict__ c2n,
                                               const float* __restrict__ rowpart,
                                               float* __restrict__ out_g,
                                               float* __restrict__ out_div) {
    const int t = threadIdx.x, ii = t >> 4, jj = t & 15;
    float s = 0.f;
    for (int h = 0; h < 256; ++h) s += c1n[ii * 256 + h] * c2n[jj * 256 + h];
    out_g[ii * 16 + jj] = s;
    float ds = 0.f;
    for (int i = t; i < 8192; i += 256) ds += rowpart[i];
    #pragma unroll
    for (int o = 32; o; o >>= 1) ds += __shfl_xor(ds, o);
    __shared__ float red[4];
    if ((t & 63) == 0) red[t >> 6] = ds;
    __syncthreads();
    if (t == 0) out_div[0] = (red[0] + red[1] + red[2] + red[3]) * (1.f / 8192.f);
}

// ---------------------------------------------------------------------------
// Workspace layout (bytes). End = 58,195,968 (< prior validated 70 MB).
// No region aliasing this round.
// ---------------------------------------------------------------------------
static constexpr long OFF_SEQ_BF  = 0;                  // [8192,128] bf16, 2MB
static constexpr long OFF_FC1T    = 2097152;            // [2][256][128] stacked fc1|fc2
static constexpr long OFF_QWT     = 2228224;            // [512][256] stacked q|k
static constexpr long OFF_VW1T    = 2490368;            // [256][256]
static constexpr long OFF_VW2T    = 2621440;            // [256][256]
static constexpr long OFF_ROWPART = 2752512;            // 8192 f32
static constexpr long OFF_C1N     = 2785280;            // [16][256] f32
static constexpr long OFF_C2N     = 2801664;
static constexpr long OFF_ADJ     = 3145728;            // adj_bf 8MB
static constexpr long OFF_DIFF    = 11534336;           // diff_bf 8MB
static constexpr long OFF_FTST    = 19922944;           // [2][256][8192] ftsT|fts2T 8MB
static constexpr long OFF_OUTT    = 28311552;           // [16][256][512] 4MB
static constexpr long OFF_OUTBF   = 32505856;           // [16][512][256] 4MB
static constexpr long OFF_QBF     = 36700160;           // [8192][256] 4MB
static constexpr long OFF_KBF     = 40894464;           // 4MB
static constexpr long OFF_AGG     = 45088768;           // 4MB
static constexpr long OFF_PSUM    = 49283072;           // psum1 256KB | psum2 256KB
static constexpr long OFF_N1      = 49807360;           // 4MB
static constexpr long OFF_N2      = 54001664;           // 4MB

extern "C" void kernel_launch(void* const* d_in, const int* in_sizes, int n_in,
                              void* d_out, int out_size, void* d_ws, size_t ws_size,
                              hipStream_t stream) {
    const float* seq      = (const float*)d_in[0];
    const float* adj      = (const float*)d_in[1];
    const float* diff     = (const float*)d_in[2];
    const float* drop     = (const float*)d_in[3];
    const float* fc1_w    = (const float*)d_in[4];
    const float* q_w      = (const float*)d_in[5];
    const float* k_w      = (const float*)d_in[6];
    const float* v_w1     = (const float*)d_in[7];
    const float* v_w2     = (const float*)d_in[8];
    const float* fc2_w    = (const float*)d_in[9];
    const float* bias1    = (const float*)d_in[10];
    const float* bias2    = (const float*)d_in[11];
    const float* prelu1_a = (const float*)d_in[12];
    const float* prelu2_a = (const float*)d_in[13];
    const float* v_prelu  = (const float*)d_in[14];
    float* out = (float*)d_out;

    char* ws = (char*)d_ws;
    unsigned short* seq_bf  = (unsigned short*)(ws + OFF_SEQ_BF);
    unsigned short* fc1T    = (unsigned short*)(ws + OFF_FC1T);          // fc2T = +32768 elems
    unsigned short* fc2T    = (unsigned short*)(ws + OFF_FC1T + 65536);
    unsigned short* qwT     = (unsigned short*)(ws + OFF_QWT);           // kwT contiguous
    unsigned short* kwT     = (unsigned short*)(ws + OFF_QWT + 131072);
    unsigned short* vw1T    = (unsigned short*)(ws + OFF_VW1T);
    unsigned short* vw2T    = (unsigned short*)(ws + OFF_VW2T);
    float*          rowpart = (float*)(ws + OFF_ROWPART);
    float*          c1n     = (float*)(ws + OFF_C1N);
    float*          c2n     = (float*)(ws + OFF_C2N);
    unsigned short* adj_bf  = (unsigned short*)(ws + OFF_ADJ);
    unsigned short* diff_bf = (unsigned short*)(ws + OFF_DIFF);
    unsigned short* ftsT    = (unsigned short*)(ws + OFF_FTST);          // [2][256][8192]
    unsigned short* fts2T   = (unsigned short*)(ws + OFF_FTST + 4194304);
    unsigned short* outT    = (unsigned short*)(ws + OFF_OUTT);
    unsigned short* out_bf  = (unsigned short*)(ws + OFF_OUTBF);
    unsigned short* q_bf    = (unsigned short*)(ws + OFF_QBF);
    unsigned short* k_bf    = (unsigned short*)(ws + OFF_KBF);
    unsigned short* agg_bf  = (unsigned short*)(ws + OFF_AGG);
    float*          psum1   = (float*)(ws + OFF_PSUM);
    float*          psum2   = (float*)(ws + OFF_PSUM + 262144);
    unsigned short* n1_bf   = (unsigned short*)(ws + OFF_N1);
    unsigned short* n2_bf   = (unsigned short*)(ws + OFF_N2);

    // 1-2: conversions
    conv3<<<9216, 256, 0, stream>>>(seq, adj, diff, seq_bf, adj_bf, diff_bf);
    wtrans6<<<dim3(8, 8, 6), dim3(32, 8), 0, stream>>>(
        fc1_w, fc2_w, q_w, k_w, v_w1, v_w2, fc1T, fc2T, qwT, kwT, vw1T, vw2T);

    // 3: ftsT|fts2T = [fc1|fc2]^T @ seq^T  (batched z=2)
    gemm_nt<64, 0, false, true, false, false><<<dim3(64, 4, 2), 256, 0, stream>>>(
        fc1T, seq_bf, nullptr, ftsT, nullptr,
        256, 8192, 128, 128, 128, 8192, 0, 32768, 0, 2097152, 0, nullptr, nullptr);

    // 4: out = adj @ fts (batched), dual-write out_bf + outT
    gemm_nt<64, 0, false, true, true, false><<<dim3(2, 8, 16), 256, 0, stream>>>(
        adj_bf, ftsT, nullptr, out_bf, outT,
        512, 256, 512, 512, 8192, 256, 512, 262144, 512, 131072, 131072, nullptr, nullptr);

    // 5: h2 branch: n2_bf + psum2 (independent of attention chain)
    gemm_norm<<<dim3(1, 16, 16), 256, 0, stream>>>(
        diff_bf, fts2T, n2_bf, psum2, bias2, prelu2_a, 512, 512, 8192, 262144, 512);

    // 6: q,k projection + l2norm -> q_bf, k_bf
    qk_proj<<<256, 256, 0, stream>>>(out_bf, qwT, q_bf, k_bf);

    // 7: fused attention (scores+softmax*drop+PV) + div_loss row parts
    att_fused<<<dim3(16, 16), 256, 0, stream>>>(
        q_bf, k_bf, adj_bf, drop, outT, agg_bf, rowpart);

    // 8: fused MLP + norm -> n1_bf + psum1
    mlp_norm<<<256, 256, 0, stream>>>(
        agg_bf, vw1T, vw2T, bias1, v_prelu, prelu1_a, n1_bf, psum1);

    // 9-10: readout
    creduce<<<32, 256, 0, stream>>>(psum1, psum2, c1n, c2n);
    graphf3<<<1, 256, 0, stream>>>(c1n, c2n, rowpart, out + 67108864, out + 67109120);

    // 11: node_logits = n1 @ n2^T, XCD-swizzled
    gemm_nt<128, 0, true, false, false, true><<<dim3(64, 64, 1), 256, 0, stream>>>(
        n1_bf, n2_bf, out, nullptr, nullptr,
        8192, 8192, 256, 256, 256, 8192, 0, 0, 0, 0, 0, nullptr, nullptr);

    (void)in_sizes; (void)n_in; (void)out_size; (void)ws_size;
}